// Round 6
// baseline (520.750 us; speedup 1.0000x reference)
//
#include <hip/hip_runtime.h>

#define NND 10000
#define EE  60000
#define DD  3000
#define HH  512
#define LL  128
#define PP  256
#define NM  3000

// padded dims for the big MFMA GEMM (no tail guards in hot loop)
#define KP  3072            // 48 * 64
#define MP  10240           // 32 * 320
#define NW  1024            // [sW1|tW1] fused width, 8*128
#define KTILES (KP/64)      // 48

// gemm320 tile geometry
#define BMT 320
#define BNT 128
#define AH_STR 10240        // elems per A k-half (320 rows x 32)
#define AB_STR 20480        // elems per A buf (2 k-halves)
#define BH_STR 4096         // elems per B k-half (128 rows x 32)
#define BB_STR 8192         // elems per B buf

typedef short bf16x8 __attribute__((ext_vector_type(8)));
typedef float f32x4 __attribute__((ext_vector_type(4)));

// All scratch lives in module BSS -> no dependency on harness ws_size.
__device__ __align__(256) char g_ws[(size_t)176 << 20];

__device__ __forceinline__ unsigned short f2b(float f){
    unsigned int x = __float_as_uint(f);
    unsigned int r = x + 0x7FFFu + ((x >> 16) & 1u);
    return (unsigned short)(r >> 16);
}
__device__ __forceinline__ float b2f(unsigned short u){
    return __uint_as_float(((unsigned int)u) << 16);
}
// uint holding 2 bf16 (low = col c, high = col c+1)
__device__ __forceinline__ float2 bpair(unsigned int u){
    float2 r;
    r.x = __uint_as_float(u << 16);
    r.y = __uint_as_float(u & 0xffff0000u);
    return r;
}
__device__ __forceinline__ unsigned int packb(float a, float b){
    return (unsigned int)f2b(a) | ((unsigned int)f2b(b) << 16);
}

__device__ __forceinline__ void gl_lds16(const void* g, void* l){
    __builtin_amdgcn_global_load_lds(
        (const __attribute__((address_space(1))) unsigned int*)g,
        (__attribute__((address_space(3))) unsigned int*)l, 16, 0, 0);
}

// ---------------- init / graph build ----------------

__global__ void init_k(int* degi, int* cursor, float* scal,
                       float* ptW, float* ntW, float* svecraw, int* ecnt){
    int i = blockIdx.x*256 + threadIdx.x;
    if (i < NND){ degi[i]=0; cursor[i]=0; }
    if (i < 80) scal[i]=0.f;           // [0]=dgi-pos [1]=dgi-neg [16..79]=cos slots
    if (i == 0) ecnt[0]=0;
    if (i < 128) svecraw[i]=0.f;
    if (i < HH){ ptW[i]=0.f; ntW[i]=0.f; }
}

// merged: degree count (i < EE) + mask flags (i < NND)
__global__ void build_k(const int* __restrict__ ei,
                        const int* __restrict__ perm, const int* __restrict__ shuf,
                        int* degi, int* flag, int* negsrc){
    int i = blockIdx.x*256 + threadIdx.x;
    if (i < EE) atomicAdd(&degi[ei[EE + i]], 1);
    if (i < NND){
        int p = perm[i];
        if (i < NM){ flag[p] = 1; negsrc[p] = -1; }
        else       { flag[p] = 0; negsrc[p] = perm[NM + shuf[i - NM]]; }
    }
}

// dinv + CSR segment allocation (order-free; per-block scan, 1 atomic/block)
__global__ __launch_bounds__(256) void alloc_k(const int* __restrict__ degi,
                                               float* dinv, int* rowptr, int* ecnt){
    __shared__ int sb[256];
    __shared__ int bbase;
    int t = threadIdx.x;
    int i = blockIdx.x*256 + t;
    int v = (i < NND) ? degi[i] : 0;
    sb[t] = v;
    __syncthreads();
    for (int off = 1; off < 256; off <<= 1){
        int x = 0;
        if (t >= off) x = sb[t - off];
        __syncthreads();
        sb[t] += x;
        __syncthreads();
    }
    if (t == 255) bbase = atomicAdd(ecnt, sb[255]);
    __syncthreads();
    if (i < NND){
        rowptr[i] = bbase + sb[t] - v;
        dinv[i] = 1.f/sqrtf((float)(degi[i] + 1));
    }
}

__global__ void fill_k(const int* __restrict__ ei, const int* __restrict__ rowptr,
                       int* cursor, int* adj){
    int i = blockIdx.x*256 + threadIdx.x;
    if (i < EE){
        int d = ei[EE + i];
        int s = ei[i];
        int p = atomicAdd(&cursor[d], 1);
        adj[rowptr[d] + p] = s;
    }
}

// token @ W1 partial sums; grid (2, 64) -> 128 blocks
__global__ __launch_bounds__(512) void tok_k(const float* __restrict__ posT,
        const float* __restrict__ negT,
        const float* __restrict__ sW1, const float* __restrict__ tW1,
        float* ptW, float* ntW){
    int b = blockIdx.x; int chunk = blockIdx.y; int j = threadIdx.x;
    const float* tok = b ? negT : posT;
    const float* Wm  = b ? tW1  : sW1;
    float acc = 0.f;
    int d0 = chunk * 47, d1 = d0 + 47; if (d1 > DD) d1 = DD;
    for (int d = d0; d < d1; ++d) acc += tok[d] * Wm[(long)d*HH + j];
    atomicAdd(&((b ? ntW : ptW)[j]), acc);
}

// ---------------- casts for MFMA path ----------------

__global__ __launch_bounds__(256) void cast_pad_x_k(const float* __restrict__ x,
                                                    unsigned short* __restrict__ xb){
    long idx = (long)blockIdx.x*256 + threadIdx.x;
    if (idx >= (long)MP*(KP/8)) return;
    int row = (int)(idx / (KP/8));
    int g   = (int)(idx % (KP/8));
    unsigned short o[8] = {0,0,0,0,0,0,0,0};
    if (row < NND && g < DD/8){
        const float* src = x + (long)row*DD + g*8;
        float4 a = *(const float4*)(src);
        float4 b = *(const float4*)(src + 4);
        o[0]=f2b(a.x); o[1]=f2b(a.y); o[2]=f2b(a.z); o[3]=f2b(a.w);
        o[4]=f2b(b.x); o[5]=f2b(b.y); o[6]=f2b(b.z); o[7]=f2b(b.w);
    }
    *(uint4*)(xb + (long)row*KP + g*8) = *(const uint4*)o;
}

// batched transpose-cast: out[c*OS + r] = bf16(in[r*C + c]), zero-fill r in [R,OS)
struct TBatch {
    const float* in[10];
    unsigned short* out[10];
    int R[10], C[10], OS[10];
    int t0[11];
};

__global__ void transbatch_k(TBatch tb){
    __shared__ unsigned short tile[32][33];
    int b = blockIdx.x;
    int d = 0;
    while (d < 9 && b >= tb.t0[d+1]) d++;
    const float* in = tb.in[d];
    unsigned short* out = tb.out[d];
    int R = tb.R[d], C = tb.C[d], OS = tb.OS[d];
    int lt = b - tb.t0[d];
    int Ctiles = (C + 31) >> 5;
    int rt = lt / Ctiles, ct = lt % Ctiles;
    int rb = rt*32, cb = ct*32;
    int tx = threadIdx.x, ty = threadIdx.y; // (32,8)
    for (int i = ty; i < 32; i += 8){
        int r = rb + i, c = cb + tx;
        tile[i][tx] = (r < R && c < C) ? f2b(in[(long)r*C + c]) : (unsigned short)0;
    }
    __syncthreads();
    for (int i = ty; i < 32; i += 8){
        int c = cb + i, r = rb + tx;
        if (c < C && r < OS) out[(long)c*OS + r] = (r < R) ? tile[tx][i] : (unsigned short)0;
    }
}

// ------ 320x128 MFMA GEMM, 256 blocks (1/CU), 1-barrier software-pipelined ------
// A: MP x KP bf16, Bg: NW x KP bf16 (row = output col). C guarded to M rows.
// A triple-buffered (3 x 40 KiB), B double-buffered (2 x 16 KiB) = 152 KiB LDS.
// Fragment reads are pipelined ONE TILE AHEAD into a second register set:
//   body(t): [S1: 4 A(t+2) gl_lds][cluster-1 regs(t)] vmcnt(4) BAR
//            [S2: 1 A + 2 B(t+2) gl_lds][18 ds_reads frags(t+1)][cluster-2 regs(t)]
// so reads have ~1 full tile of lead time and there is ONE barrier per tile.
// Hazards (1-barrier gap suffices):
//  - reads of frags(t) drain per-wave before cluster-1(t) (lgkm dep), which
//    precedes BAR(t); earliest overwrite of those buffers is staging after
//    BAR(t+1)  -> safe for A (a0 reused at t+3) and B (buf reused at t+2).
//  - vmcnt FIFO at GATE of body t: outstanding = prev body's 7 + this S1's 4;
//    vmcnt(4) drains exactly tile (t+1)'s staging; BAR makes it cross-wave
//    visible before the frags(t+1) reads.
// Swizzle (both-sides, rule 21): linear LDS dest; global source chunk pre-XOR'd
// with ((row>>3)&1)<<1; reads XOR the same involution. Zero bank conflicts (meas.).
// Main loop unrolled x2 with named frag sets A/B (rule #20: static indexing).

#define LDA(PB, MT, KS) (*(const bf16x8*)&As[(PB) + (KS)*AH_STR + a_off + (MT)*512])
#define LDB(PB, NT, KS) (*(const bf16x8*)&Bs[(PB) + (KS)*BH_STR + b_off + (NT)*512])

#define STG_A(KT, PDST, P) gl_lds16(asrc[P] + ((KT)<<6), &As[(PDST) + adst[P]])
#define STG_B(KT, PDST, Q) gl_lds16(bsrc[Q] + ((KT)<<6), &Bs[(PDST) + bdst[Q]])

#define GATE4 asm volatile("s_waitcnt vmcnt(4)" ::: "memory")
#define GATE0 asm volatile("s_waitcnt vmcnt(0)" ::: "memory")
#define AFENCE asm volatile("" ::: "memory")
#define BARR  { AFENCE; __builtin_amdgcn_s_barrier(); AFENCE; }

#define CL1(AF, BF)                                                               \
    __builtin_amdgcn_s_setprio(1);                                                \
    _Pragma("unroll") for (int ks = 0; ks < 2; ++ks)                              \
      _Pragma("unroll") for (int nt = 0; nt < 4; ++nt)                            \
        _Pragma("unroll") for (int mt = 0; mt < 2; ++mt)                          \
          acc[mt][nt] = __builtin_amdgcn_mfma_f32_16x16x32_bf16(AF[mt][ks], BF[nt][ks], acc[mt][nt], 0,0,0); \
    __builtin_amdgcn_s_setprio(0);

#define CL2(AF, BF)                                                               \
    __builtin_amdgcn_s_setprio(1);                                                \
    _Pragma("unroll") for (int ks = 0; ks < 2; ++ks)                              \
      _Pragma("unroll") for (int nt = 0; nt < 4; ++nt)                            \
        _Pragma("unroll") for (int mt = 2; mt < 5; ++mt)                          \
          acc[mt][nt] = __builtin_amdgcn_mfma_f32_16x16x32_bf16(AF[mt][ks], BF[nt][ks], acc[mt][nt], 0,0,0); \
    __builtin_amdgcn_s_setprio(0);

#define RDF(AF, BF, PA, PB)                                                       \
    _Pragma("unroll") for (int nt = 0; nt < 4; ++nt){                             \
        BF[nt][0] = LDB(PB, nt, 0); BF[nt][1] = LDB(PB, nt, 1); }                 \
    _Pragma("unroll") for (int mt = 0; mt < 5; ++mt){                             \
        AF[mt][0] = LDA(PA, mt, 0); AF[mt][1] = LDA(PA, mt, 1); }

__global__ __launch_bounds__(512, 2) void gemm320(
    const unsigned short* __restrict__ Ag,
    const unsigned short* __restrict__ Bg,
    unsigned short* __restrict__ C,
    int M, int Cstride)
{
    __shared__ __align__(1024) unsigned short As[3*AB_STR]; // 120 KiB
    __shared__ __align__(1024) unsigned short Bs[2*BB_STR]; //  32 KiB

    // bijective XCD-chunked swizzle (nwg = 256, 256 % 8 == 0)
    const int bid = blockIdx.x;
    const int swz = (bid & 7)*32 + (bid >> 3);
    const int m0 = (swz >> 3) * BMT;   // 32 m-tiles
    const int n0 = (swz & 7) * BNT;    // 8 n-tiles

    const int tid = threadIdx.x;
    const int w   = tid >> 6,  l = tid & 63;
    const int wm  = w >> 1,    wn = w & 1;      // 4(M) x 2(N) wave grid: 80x64/wave
    const int l16 = l & 15,    quad = l >> 4;

    // staging: lane l writes LDS row (g*16 + l>>2), physical chunk (l&3);
    // global source chunk pre-swizzled by row-bit3 = l bit5.
    const int schunk = (l & 3) ^ (((l >> 5) & 1) << 1);
    // reads: logical chunk 'quad' -> physical chunk quad ^ ((row>>3)&1)<<1
    const int rq8   = ((quad ^ (((l16 >> 3) & 1) << 1)) << 3);
    const int a_off = ((wm*80 + l16) << 5) + rq8;
    const int b_off = ((wn*64 + l16) << 5) + rq8;

    // per-wave staging source pointers / LDS dest offsets (static-indexed)
    const unsigned short* asrc[5]; int adst[5];
    #pragma unroll
    for (int p = 0; p < 5; ++p){
        int j = 5*w + p, kh = j/20, g = j - kh*20;
        asrc[p] = Ag + (long)(m0 + g*16 + (l >> 2))*KP + (kh << 5) + (schunk << 3);
        adst[p] = kh*AH_STR + g*512;
    }
    const unsigned short* bsrc[2]; int bdst[2];
    #pragma unroll
    for (int q = 0; q < 2; ++q){
        int j = 2*w + q, kh = j >> 3, g = j & 7;
        bsrc[q] = Bg + (long)(n0 + g*16 + (l >> 2))*KP + (kh << 5) + (schunk << 3);
        bdst[q] = kh*BH_STR + g*512;
    }

    f32x4 acc[5][4];
    #pragma unroll
    for (int i = 0; i < 5; ++i)
        #pragma unroll
        for (int j = 0; j < 4; ++j)
            #pragma unroll
            for (int r = 0; r < 4; ++r) acc[i][j][r] = 0.f;

    bf16x8 afA[5][2], bfA[4][2], afB[5][2], bfB[4][2];

    // prologue: A(0),B(0)->buf0 [7], A(1),B(1)->buf1 [7]; drain tile-0's 7;
    // then read frags(0) into set A.
    #pragma unroll
    for (int p = 0; p < 5; ++p) STG_A(0, 0, p);
    #pragma unroll
    for (int q = 0; q < 2; ++q) STG_B(0, 0, q);
    #pragma unroll
    for (int p = 0; p < 5; ++p) STG_A(1, AB_STR, p);
    #pragma unroll
    for (int q = 0; q < 2; ++q) STG_B(1, BB_STR, q);
    asm volatile("s_waitcnt vmcnt(7)" ::: "memory");
    BARR;
    RDF(afA, bfA, 0, 0);

    int ab = 0;   // == t%3 at pair start (t even)
    #pragma unroll 1
    for (int p = 0; p < (KTILES-2)/2; ++p){   // 23 pairs, t = 2p and 2p+1
        const int t  = 2*p;
        const int a0 = ab*AB_STR;
        const int a1 = ((ab == 2) ? 0 : ab + 1)*AB_STR;   // (t+1)%3
        const int a2 = ((ab == 0) ? 2 : ab - 1)*AB_STR;   // (t+2)%3
        // ---- even body: compute t (set A), read frags(t+1) -> set B ----
        STG_A(t+2, a2, 0); STG_A(t+2, a2, 1); STG_A(t+2, a2, 2); STG_A(t+2, a2, 3);
        CL1(afA, bfA);
        GATE4; BARR;
        STG_A(t+2, a2, 4); STG_B(t+2, 0, 0); STG_B(t+2, 0, 1);
        RDF(afB, bfB, a1, BB_STR);
        CL2(afA, bfA);
        // ---- odd body: compute t+1 (set B), read frags(t+2) -> set A ----
        STG_A(t+3, a0, 0); STG_A(t+3, a0, 1); STG_A(t+3, a0, 2); STG_A(t+3, a0, 3);
        CL1(afB, bfB);
        GATE4; BARR;
        STG_A(t+3, a0, 4); STG_B(t+3, BB_STR, 0); STG_B(t+3, BB_STR, 1);
        RDF(afA, bfA, a2, 0);
        CL2(afB, bfB);
        ab = (ab == 0) ? 2 : ab - 1;   // (ab+2)%3
    }
    // peel tile 46 (set A): no staging; drain tile-47's staging; read frags(47).
    {
        const int a1 = ((ab == 2) ? 0 : ab + 1)*AB_STR;   // 47%3
        CL1(afA, bfA);
        GATE0; BARR;
        RDF(afB, bfB, a1, BB_STR);
        CL2(afA, bfA);
    }
    // peel tile 47 (set B): registers only.
    CL1(afB, bfB);
    CL2(afB, bfB);

    // epilogue: C/D layout col=lane&15, row=quad*4+reg
    #pragma unroll
    for (int mt = 0; mt < 5; ++mt){
        const int rowb = m0 + wm*80 + mt*16 + quad*4;
        #pragma unroll
        for (int nt = 0; nt < 4; ++nt){
            const int col = n0 + wn*64 + nt*16 + l16;
            #pragma unroll
            for (int r = 0; r < 4; ++r){
                const int row = rowb + r;
                if (row < M) C[(long)row*Cstride + col] = f2b(acc[mt][nt][r]);
            }
        }
    }
}

// ---------------- 64x64 MFMA GEMM: C = A[ridx?] @ BT^T (+epi) ----------------
// A: MxK bf16, BT: NnxK bf16, K % 32 == 0. epi: 0 none, 1 +bias, 2 +bias+prelu.
// obf: output bf16 (else f32). ridx: optional A row gather.
__device__ __forceinline__ void gemm_bt_body(
    const unsigned short* __restrict__ A,
    const unsigned short* __restrict__ BT,
    void* __restrict__ Cv,
    int M, int Nn, int K, int Cstride,
    const float* __restrict__ bias,
    const float* __restrict__ alpha,
    int epi, const int* __restrict__ ridx, int obf)
{
    __shared__ __align__(16) unsigned short As[64*40];
    __shared__ __align__(16) unsigned short Bs[64*40];
    const int m0 = blockIdx.y*64, n0 = blockIdx.x*64;
    const int t = threadIdx.x;
    const int lrow = t >> 2, lk = (t & 3) * 8;
    const int wave = t >> 6, lane = t & 63;
    const int quad = lane >> 4, l16 = lane & 15;
    f32x4 acc[4];
    #pragma unroll
    for (int i = 0; i < 4; i++)
        for (int j = 0; j < 4; j++) acc[i][j] = 0.f;

    const bool arv = (m0 + lrow) < M;
    const bool brv = (n0 + lrow) < Nn;
    long arow = 0;
    if (arv) arow = ridx ? (long)ridx[m0 + lrow] : (long)(m0 + lrow);
    const long arowbase = arow * K;
    const long browbase = (long)(n0 + lrow) * K;

    for (int k0 = 0; k0 < K; k0 += 32){
        int gk = k0 + lk;
        uint4 av = {0u,0u,0u,0u};
        uint4 bv = {0u,0u,0u,0u};
        if (arv) av = *(const uint4*)(A + arowbase + gk);
        if (brv) bv = *(const uint4*)(BT + browbase + gk);
        *(uint4*)(&As[lrow*40 + lk]) = av;
        *(uint4*)(&Bs[lrow*40 + lk]) = bv;
        __syncthreads();
        bf16x8 af = *(const bf16x8*)(&As[(wave*16 + l16)*40 + quad*8]);
        #pragma unroll
        for (int nt = 0; nt < 4; nt++){
            bf16x8 bfr = *(const bf16x8*)(&Bs[(nt*16 + l16)*40 + quad*8]);
            acc[nt] = __builtin_amdgcn_mfma_f32_16x16x32_bf16(af, bfr, acc[nt], 0, 0, 0);
        }
        __syncthreads();
    }

    const int rowb = m0 + wave*16 + quad*4;
    float aval = (epi == 2) ? alpha[0] : 0.f;
    #pragma unroll
    for (int nt = 0; nt < 4; nt++){
        int col = n0 + nt*16 + l16;
        if (col >= Nn) continue;
        float bvv = epi ? bias[col] : 0.f;
        #pragma unroll
        for (int r = 0; r < 4; r++){
            int row = rowb + r;
            if (row < M){
                float v = acc[nt][r] + bvv;
                if (epi == 2 && v < 0.f) v *= aval;
                if (obf) ((unsigned short*)Cv)[(long)row*Cstride + col] = f2b(v);
                else     ((float*)Cv)[(long)row*Cstride + col] = v;
            }
        }
    }
}

__global__ __launch_bounds__(256) void gemm_bt_ex(
    const unsigned short* __restrict__ A,
    const unsigned short* __restrict__ BT,
    void* __restrict__ Cv,
    int M, int Nn, int K, int Cstride,
    const float* __restrict__ bias,
    const float* __restrict__ alpha,
    int epi, const int* __restrict__ ridx, int obf)
{
    gemm_bt_body(A, BT, Cv, M, Nn, K, Cstride, bias, alpha, epi, ridx, obf);
}

// z-batched pair variant: blockIdx.z selects the (A,B,C,bias,alpha) set.
__global__ __launch_bounds__(256) void gemm_bt2(
    const unsigned short* __restrict__ A0, const unsigned short* __restrict__ A1,
    const unsigned short* __restrict__ B0, const unsigned short* __restrict__ B1,
    void* __restrict__ C0, void* __restrict__ C1,
    int M, int Nn, int K, int Cstride,
    const float* __restrict__ bias0, const float* __restrict__ bias1,
    const float* __restrict__ al0, const float* __restrict__ al1,
    int epi, const int* __restrict__ ridx, int obf)
{
    if (blockIdx.z == 0)
        gemm_bt_body(A0, B0, C0, M, Nn, K, Cstride, bias0, al0, epi, ridx, obf);
    else
        gemm_bt_body(A1, B1, C1, M, Nn, K, Cstride, bias1, al1, epi, ridx, obf);
}

// 3-way fused launch: z=0/1 = projection-H (pos/neg, gathered rows, prelu),
// z=2 = decoder pre-matmul recPre (independent of both). Ragged grid with
// early-exit guards; launch (4, 157, 3).
__global__ __launch_bounds__(256) void gemm_bt3(
    const unsigned short* __restrict__ repP, const unsigned short* __restrict__ repN,
    const unsigned short* __restrict__ pW1T, const unsigned short* __restrict__ tpW1T,
    const unsigned short* __restrict__ e2dWT,
    unsigned short* __restrict__ posH, unsigned short* __restrict__ negH,
    unsigned short* __restrict__ recPre,
    const float* __restrict__ pb1, const float* __restrict__ tpb1,
    const float* __restrict__ pa, const float* __restrict__ tpa,
    const int* __restrict__ perm)
{
    int z = blockIdx.z;
    if (z == 0){
        if (blockIdx.y < 47)
            gemm_bt_body(repP, pW1T, posH, NM, PP, LL, PP, pb1, pa, 2, perm, 1);
    } else if (z == 1){
        if (blockIdx.y < 47)
            gemm_bt_body(repN, tpW1T, negH, NM, PP, LL, PP, tpb1, tpa, 2, perm, 1);
    } else {
        if (blockIdx.x < 2)
            gemm_bt_body(repP, e2dWT, recPre, NND, LL, LL, LL, nullptr, nullptr, 0, nullptr, 1);
    }
}

// ---------------- fused GCN layer-1 aggregation (pos + neg), bf16 I/O ----------------

__global__ __launch_bounds__(256) void agg1_k(const unsigned short* __restrict__ XW,
    const float* __restrict__ ptW, const float* __restrict__ ntW,
    const int* __restrict__ flag, const int* __restrict__ negsrc,
    const float* __restrict__ dinv, const int* __restrict__ rowptr,
    const int* __restrict__ degi, const int* __restrict__ adj,
    const float* __restrict__ sb1, const float* __restrict__ sav,
    const float* __restrict__ tb1, const float* __restrict__ tav,
    unsigned short* __restrict__ H1p, unsigned short* __restrict__ H1n)
{
    int i = blockIdx.x; int t = threadIdx.x;
    int c = 2*t;                       // cols c, c+1 in [0,512)
    float di = dinv[i];
    int rs = rowptr[i], re = rs + degi[i];
    float p0 = ptW[c], p1 = ptW[c+1];
    float n0v = ntW[c], n1v = ntW[c+1];
    int fi = flag[i];
    int nsi = negsrc[i]; if (nsi < 0) nsi = 0;
    float ffi = fi ? 1.f : 0.f;
    float2 xp = bpair(*(const unsigned int*)(XW + (long)i*1024 + c));
    float2 xn = bpair(*(const unsigned int*)(XW + (long)nsi*1024 + 512 + c));
    float pa0 = (xp.x + ffi*p0) * di;
    float pa1 = (xp.y + ffi*p1) * di;
    float na0 = (fi ? n0v : xn.x) * di;
    float na1 = (fi ? n1v : xn.y) * di;
    for (int e = rs; e < re; ++e){
        int s = adj[e]; float ds = dinv[s];
        int fs = flag[s];
        int ns = negsrc[s]; if (ns < 0) ns = 0;
        float ffs = fs ? 1.f : 0.f;
        float2 sp = bpair(*(const unsigned int*)(XW + (long)s*1024 + c));
        float2 sn = bpair(*(const unsigned int*)(XW + (long)ns*1024 + 512 + c));
        pa0 += (sp.x + ffs*p0) * ds;
        pa1 += (sp.y + ffs*p1) * ds;
        na0 += (fs ? n0v : sn.x) * ds;
        na1 += (fs ? n1v : sn.y) * ds;
    }
    float sa_ = sav[0], ta_ = tav[0];
    float v0 = di*pa0 + sb1[c];   if (v0 < 0.f) v0 *= sa_;
    float v1 = di*pa1 + sb1[c+1]; if (v1 < 0.f) v1 *= sa_;
    float w0 = di*na0 + tb1[c];   if (w0 < 0.f) w0 *= ta_;
    float w1 = di*na1 + tb1[c+1]; if (w1 < 0.f) w1 *= ta_;
    *(unsigned int*)(H1p + (long)i*512 + c) = packb(v0, v1);
    *(unsigned int*)(H1n + (long)i*512 + c) = packb(w0, w1);
}

// fused pos/neg second-layer aggregation: blockIdx.y selects the set.
__global__ __launch_bounds__(128) void agg128_k(
    const unsigned short* __restrict__ In0, const unsigned short* __restrict__ In1,
    const float* __restrict__ dinv, const int* __restrict__ rowptr,
    const int* __restrict__ degi, const int* __restrict__ adj,
    const float* __restrict__ b20, const float* __restrict__ b21,
    const float* __restrict__ a20, const float* __restrict__ a21,
    unsigned short* __restrict__ Out0, unsigned short* __restrict__ Out1)
{
    int i = blockIdx.x, t = threadIdx.x;
    int h = blockIdx.y;
    const unsigned short* In = h ? In1 : In0;
    const float* b2 = h ? b21 : b20;
    const float* a2 = h ? a21 : a20;
    unsigned short* Out = h ? Out1 : Out0;
    float di = dinv[i];
    int rs = rowptr[i], re = rs + degi[i];
    float acc = b2f(In[(long)i*128 + t]) * di;
    for (int e = rs; e < re; ++e){
        int s = adj[e];
        acc += b2f(In[(long)s*128 + t]) * dinv[s];
    }
    float v = di*acc + b2[t];
    float a = a2[0]; if (v < 0.f) v *= a;
    Out[(long)i*128 + t] = f2b(v);
}

__global__ __launch_bounds__(128) void aggrec_k(const unsigned short* __restrict__ recPre,
    const float* __restrict__ dinv, const int* __restrict__ rowptr,
    const int* __restrict__ degi, const int* __restrict__ adj,
    const int* __restrict__ flag, const int* __restrict__ perm,
    unsigned short* __restrict__ recAgg)
{
    int b = blockIdx.x, t = threadIdx.x;
    int i = perm[b];
    float di = dinv[i];
    int rs = rowptr[i], re = rs + degi[i];
    float acc = 0.f; // self loop: i is a mask node -> rec row zeroed
    for (int e = rs; e < re; ++e){
        int s = adj[e];
        if (!flag[s]) acc += b2f(recPre[(long)s*128 + t]) * dinv[s];
    }
    recAgg[(long)b*128 + t] = f2b(di * acc);
}

// ---------------- DGI head ----------------

__global__ __launch_bounds__(128) void meanp_k(const float* __restrict__ posZ,
                                               float* svecraw){
    int j = threadIdx.x;
    int r0 = blockIdx.x*64, r1 = r0 + 64; if (r1 > NM) r1 = NM;
    float s = 0.f;
    for (int r = r0; r < r1; ++r) s += posZ[(long)r*128 + j];
    atomicAdd(&svecraw[j], s);
}

__global__ void ws_k(const float* __restrict__ dgiW, const float* __restrict__ svecraw,
                     float* wsv){
    __shared__ float s[128];
    int i = threadIdx.x; // 128
    s[i] = 1.f/(1.f + expf(-svecraw[i]/(float)NM));
    __syncthreads();
    float a = 0.f;
    for (int j = 0; j < 128; ++j) a += dgiW[i*128 + j] * s[j];
    wsv[i] = a;
}

// grid-stride rows; per-wave accumulate; 2 atomics per block.
__global__ __launch_bounds__(256) void dgi_k(const float* __restrict__ posZ,
    const float* __restrict__ negZ, const float* __restrict__ wsv, float* scal){
    __shared__ float sp[4], sn[4];
    int wid = threadIdx.x >> 6, lane = threadIdx.x & 63;
    float w0 = wsv[lane], w1 = wsv[64 + lane];
    float accp = 0.f, accn = 0.f;
    for (int row = blockIdx.x*4 + wid; row < 2*NM; row += gridDim.x*4){
        const float* Z = (row < NM) ? posZ : negZ;
        int r = (row < NM) ? row : row - NM;
        float v = Z[(long)r*128 + lane] * w0 + Z[(long)r*128 + 64 + lane] * w1;
        for (int off = 32; off; off >>= 1) v += __shfl_down(v, off, 64);
        if (lane == 0){
            float d = 1.f/(1.f + expf(-v));
            if (row < NM) accp += logf(d + 1e-15f);
            else          accn += logf(1.f - d + 1e-15f);
        }
    }
    if (lane == 0){ sp[wid] = accp; sn[wid] = accn; }
    __syncthreads();
    if (threadIdx.x == 0){
        atomicAdd(&scal[0], sp[0]+sp[1]+sp[2]+sp[3]);
        atomicAdd(&scal[1], sn[0]+sn[1]+sn[2]+sn[3]);
    }
}

// ---------------- cosine feature loss ----------------

__global__ __launch_bounds__(256) void cos_k(const float* __restrict__ x,
    const unsigned short* __restrict__ recMask, const int* __restrict__ perm,
    float* scal){
    int b = blockIdx.x, t = threadIdx.x;
    long xi = (long)perm[b]*DD;
    long ri = (long)b*DD;
    float dot = 0.f, nx = 0.f, nr = 0.f;
    for (int d = t; d < DD; d += 256){
        float xv = x[xi + d], rv = b2f(recMask[ri + d]);
        dot += xv*rv; nx += xv*xv; nr += rv*rv;
    }
    for (int off = 32; off; off >>= 1){
        dot += __shfl_down(dot, off, 64);
        nx  += __shfl_down(nx,  off, 64);
        nr  += __shfl_down(nr,  off, 64);
    }
    __shared__ float sd[4], sx[4], sr[4];
    int w = t >> 6, lane = t & 63;
    if (lane == 0){ sd[w] = dot; sx[w] = nx; sr[w] = nr; }
    __syncthreads();
    if (t == 0){
        float Dv = sd[0]+sd[1]+sd[2]+sd[3];
        float Xv = sx[0]+sx[1]+sx[2]+sx[3];
        float Rv = sr[0]+sr[1]+sr[2]+sr[3];
        float c = Dv/(fmaxf(sqrtf(Xv),1e-12f)*fmaxf(sqrtf(Rv),1e-12f));
        float e = 1.f - c;
        atomicAdd(&scal[16 + (b & 63)], e*e);   // 64-way spread -> ~47 per slot
    }
}

__global__ void fin_k(const float* __restrict__ scal, float* out){
    float fs = 0.f;
    for (int i = 0; i < 64; ++i) fs += scal[16 + i];
    float feat = fs/(float)NM;
    float dgi  = -(scal[0]/(float)NM) - (scal[1]/(float)NM);
    out[0] = feat;
    out[1] = dgi;
}

// ---------------- launch ----------------

extern "C" void kernel_launch(void* const* d_in, const int* in_sizes, int n_in,
                              void* d_out, int out_size, void* d_ws, size_t ws_size,
                              hipStream_t stream) {
    (void)in_sizes; (void)n_in; (void)out_size; (void)d_ws; (void)ws_size;
    const float* x  = (const float*)d_in[0];
    const int* ei   = (const int*)d_in[1];
    const int* perm = (const int*)d_in[2];
    const int* shuf = (const int*)d_in[3];
    const float* sW1 = (const float*)d_in[4];
    const float* sb1 = (const float*)d_in[5];
    const float* sa  = (const float*)d_in[6];
    const float* sW2 = (const float*)d_in[7];
    const float* sb2 = (const float*)d_in[8];
    const float* tW1 = (const float*)d_in[9];
    const float* tb1 = (const float*)d_in[10];
    const float* ta  = (const float*)d_in[11];
    const float* tW2 = (const float*)d_in[12];
    const float* tb2 = (const float*)d_in[13];
    const float* pW1 = (const float*)d_in[14];
    const float* pb1 = (const float*)d_in[15];
    const float* pa  = (const float*)d_in[16];
    const float* pW2 = (const float*)d_in[17];
    const float* pb2 = (const float*)d_in[18];
    const float* tpW1 = (const float*)d_in[19];
    const float* tpb1 = (const float*)d_in[20];
    const float* tpa  = (const float*)d_in[21];
    const float* tpW2 = (const float*)d_in[22];
    const float* tpb2 = (const float*)d_in[23];
    const float* dgiW = (const float*)d_in[24];
    const float* posT = (const float*)d_in[25];
    const float* negT = (const float*)d_in[26];
    const float* e2dW = (const float*)d_in[27];
    const float* dW   = (const float*)d_in[28];
    const float* db   = (const float*)d_in[29];
    float* out = (float*)d_out;

    void* wsp = nullptr;
    hipGetSymbolAddress(&wsp, HIP_SYMBOL(g_ws));
    char* base = (char*)wsp;
    size_t off = 0;
    auto alloc = [&](size_t b){ size_t o = off; off = (off + b + 255) & ~(size_t)255; return o; };

    float* dinv    = (float*)(base + alloc(NND*4));
    int* degi      = (int*)  (base + alloc(NND*4));
    int* rowptr    = (int*)  (base + alloc(NND*4));
    int* cursor    = (int*)  (base + alloc(NND*4));
    int* adj       = (int*)  (base + alloc(EE*4));
    int* flag      = (int*)  (base + alloc(NND*4));
    int* negsrc    = (int*)  (base + alloc(NND*4));
    int* ecnt      = (int*)  (base + alloc(16*4));
    float* ptW     = (float*)(base + alloc(HH*4));
    float* ntW     = (float*)(base + alloc(HH*4));
    float* svecraw = (float*)(base + alloc(128*4));
    float* wsv     = (float*)(base + alloc(128*4));
    float* scal    = (float*)(base + alloc(80*4));

    unsigned short* xb    = (unsigned short*)(base + alloc((size_t)MP*KP*2));
    unsigned short* W1T   = (unsigned short*)(base + alloc((size_t)NW*KP*2));
    unsigned short* sW2T  = (unsigned short*)(base + alloc((size_t)LL*HH*2));
    unsigned short* tW2T  = (unsigned short*)(base + alloc((size_t)LL*HH*2));
    unsigned short* pW1T  = (unsigned short*)(base + alloc((size_t)PP*LL*2));
    unsigned short* pW2T  = (unsigned short*)(base + alloc((size_t)LL*PP*2));
    unsigned short* tpW1T = (unsigned short*)(base + alloc((size_t)PP*LL*2));
    unsigned short* tpW2T = (unsigned short*)(base + alloc((size_t)LL*PP*2));
    unsigned short* e2dWT = (unsigned short*)(base + alloc((size_t)LL*LL*2));
    unsigned short* dWT   = (unsigned short*)(base + alloc((size_t)DD*LL*2));

    unsigned short* XW      = (unsigned short*)(base + alloc((size_t)NND*1024*2));
    unsigned short* H1p     = (unsigned short*)(base + alloc((size_t)NND*512*2));
    unsigned short* H1n     = (unsigned short*)(base + alloc((size_t)NND*512*2));
    unsigned short* M2p     = (unsigned short*)(base + alloc((size_t)NND*128*2));
    unsigned short* M2n     = (unsigned short*)(base + alloc((size_t)NND*128*2));
    unsigned short* repP    = (unsigned short*)(base + alloc((size_t)NND*128*2));
    unsigned short* repN    = (unsigned short*)(base + alloc((size_t)NND*128*2));
    unsigned short* posH    = (unsigned short*)(base + alloc((size_t)NM*256*2));
    unsigned short* negH    = (unsigned short*)(base + alloc((size_t)NM*256*2));
    float* posZ             = (float*)(base + alloc((size_t)NM*128*4));
    float* negZ             = (float*)(base + alloc((size_t)NM*128*4));
    unsigned short* recPre  = (unsigned short*)(base + alloc((size_t)NND*128*2));
    unsigned short* recAgg  = (unsigned short*)(base + alloc((size_t)NM*128*2));
    unsigned short* recMask = (unsigned short*)(base + alloc((size_t)NM*DD*2));

    // ---- graph build (scan-free) ----
    init_k<<<(NND+255)/256, 256, 0, stream>>>(degi, cursor, scal, ptW, ntW, svecraw, ecnt);
    build_k<<<(EE+255)/256, 256, 0, stream>>>(ei, perm, shuf, degi, flag, negsrc);
    alloc_k<<<(NND+255)/256, 256, 0, stream>>>(degi, dinv, rowptr, ecnt);
    fill_k<<<(EE+255)/256, 256, 0, stream>>>(ei, rowptr, cursor, adj);
    tok_k<<<dim3(2,64), 512, 0, stream>>>(posT, negT, sW1, tW1, ptW, ntW);

    // ---- bf16 staging ----
    cast_pad_x_k<<<(int)(((long)MP*(KP/8) + 255)/256), 256, 0, stream>>>(x, xb);
    {
        TBatch tb;
        const float* ins[10] = {sW1, tW1, sW2, tW2, pW1, pW2, tpW1, tpW2, e2dW, dW};
        unsigned short* outs[10] = {W1T, W1T + (size_t)HH*KP, sW2T, tW2T, pW1T, pW2T,
                                    tpW1T, tpW2T, e2dWT, dWT};
        int Rs[10]  = {DD, DD, HH, HH, LL, PP, LL, PP, LL, LL};
        int Cs[10]  = {HH, HH, LL, LL, PP, LL, PP, LL, LL, DD};
        int OSs[10] = {KP, KP, HH, HH, LL, PP, LL, PP, LL, LL};
        int cum = 0;
        for (int d = 0; d < 10; d++){
            tb.in[d] = ins[d]; tb.out[d] = outs[d];
            tb.R[d] = Rs[d]; tb.C[d] = Cs[d]; tb.OS[d] = OSs[d];
            tb.t0[d] = cum;
            cum += (OSs[d]/32) * ((Cs[d] + 31)/32);
        }
        tb.t0[10] = cum;
        transbatch_k<<<cum, dim3(32,8), 0, stream>>>(tb);
    }

    // ---- encoder layer 1 (MFMA 320x128, 256 blocks) + fused aggregation ----
    gemm320<<<256, 512, 0, stream>>>(xb, W1T, XW, NND, 1024);
    agg1_k<<<NND, 256, 0, stream>>>(XW, ptW, ntW, flag, negsrc, dinv, rowptr, degi, adj,
                                    sb1, sa, tb1, ta, H1p, H1n);

    // ---- encoder layer 2 (MFMA, z-batched pair) + fused aggregation ----
    gemm_bt2<<<dim3(2,157,2), 256, 0, stream>>>(H1p, H1n, sW2T, tW2T, M2p, M2n,
                                                NND, LL, HH, LL,
                                                nullptr, nullptr, nullptr, nullptr,
                                                0, nullptr, 1);
    agg128_k<<<dim3(NND,2), 128, 0, stream>>>(M2p, M2n, dinv, rowptr, degi, adj,
                                              sb2, tb2, sa, ta, repP, repN);

    // ---- projections-H (pos+neg) + decoder recPre, one ragged z=3 launch ----
    gemm_bt3<<<dim3(4,157,3), 256, 0, stream>>>(repP, repN, pW1T, tpW1T, e2dWT,
                                                posH, negH, recPre,
                                                pb1, tpb1, pa, tpa, perm);
    gemm_bt2<<<dim3(2,47,2), 256, 0, stream>>>(posH, negH, pW2T, tpW2T, posZ, negZ,
                                               NM, LL, PP, LL,
                                               pb2, tpb2, nullptr, nullptr, 1, nullptr, 0);

    // ---- decoder aggregation + reconstruction ----
    aggrec_k<<<NM, 128, 0, stream>>>(recPre, dinv, rowptr, degi, adj, flag, perm, recAgg);
    gemm_bt_ex<<<dim3(47,47), 256, 0, stream>>>(recAgg, dWT, recMask, NM, DD, LL, DD,
                                                db, nullptr, 1, nullptr, 1);

    // ---- DGI loss ----
    meanp_k<<<47, 128, 0, stream>>>(posZ, svecraw);
    ws_k<<<1, 128, 0, stream>>>(dgiW, svecraw, wsv);
    dgi_k<<<128, 256, 0, stream>>>(posZ, negZ, wsv, scal);

    // ---- feature loss ----
    cos_k<<<NM, 256, 0, stream>>>(x, recMask, perm, scal);

    fin_k<<<1, 1, 0, stream>>>(scal, out);
}

// Round 7
// 496.998 us; speedup vs baseline: 1.0478x; 1.0478x over previous
//
#include <hip/hip_runtime.h>

#define NND 10000
#define EE  60000
#define DD  3000
#define HH  512
#define LL  128
#define PP  256
#define NM  3000

// padded dims for the big MFMA GEMM (no tail guards in hot loop)
#define KP  3072            // 48 * 64
#define MP  10240           // 32 * 320
#define NW  1024            // [sW1|tW1] fused width, 8*128
#define KTILES (KP/64)      // 48

// gemm320 tile geometry
#define BMT 320
#define BNT 128
#define AH_STR 10240        // elems per A k-half (320 rows x 32)
#define AB_STR 20480        // elems per A buf (2 k-halves)
#define BH_STR 4096         // elems per B k-half (128 rows x 32)
#define BB_STR 8192         // elems per B buf

typedef short bf16x8 __attribute__((ext_vector_type(8)));
typedef float f32x4 __attribute__((ext_vector_type(4)));

// All scratch lives in module BSS -> no dependency on harness ws_size.
__device__ __align__(256) char g_ws[(size_t)176 << 20];

__device__ __forceinline__ unsigned short f2b(float f){
    unsigned int x = __float_as_uint(f);
    unsigned int r = x + 0x7FFFu + ((x >> 16) & 1u);
    return (unsigned short)(r >> 16);
}
__device__ __forceinline__ float b2f(unsigned short u){
    return __uint_as_float(((unsigned int)u) << 16);
}
// uint holding 2 bf16 (low = col c, high = col c+1)
__device__ __forceinline__ float2 bpair(unsigned int u){
    float2 r;
    r.x = __uint_as_float(u << 16);
    r.y = __uint_as_float(u & 0xffff0000u);
    return r;
}
__device__ __forceinline__ unsigned int packb(float a, float b){
    return (unsigned int)f2b(a) | ((unsigned int)f2b(b) << 16);
}

__device__ __forceinline__ void gl_lds16(const void* g, void* l){
    __builtin_amdgcn_global_load_lds(
        (const __attribute__((address_space(1))) unsigned int*)g,
        (__attribute__((address_space(3))) unsigned int*)l, 16, 0, 0);
}

// ---------------- init / graph build ----------------

__global__ void init_k(int* degi, int* cursor, float* scal,
                       float* ptW, float* ntW, float* svecraw, int* ecnt){
    int i = blockIdx.x*256 + threadIdx.x;
    if (i < NND){ degi[i]=0; cursor[i]=0; }
    if (i < 80) scal[i]=0.f;           // [0]=dgi-pos [1]=dgi-neg [16..79]=cos slots
    if (i == 0) ecnt[0]=0;
    if (i < 128) svecraw[i]=0.f;
    if (i < HH){ ptW[i]=0.f; ntW[i]=0.f; }
}

// merged: degree count (i < EE) + mask flags (i < NND)
__global__ void build_k(const int* __restrict__ ei,
                        const int* __restrict__ perm, const int* __restrict__ shuf,
                        int* degi, int* flag, int* negsrc){
    int i = blockIdx.x*256 + threadIdx.x;
    if (i < EE) atomicAdd(&degi[ei[EE + i]], 1);
    if (i < NND){
        int p = perm[i];
        if (i < NM){ flag[p] = 1; negsrc[p] = -1; }
        else       { flag[p] = 0; negsrc[p] = perm[NM + shuf[i - NM]]; }
    }
}

// dinv + CSR segment allocation (order-free; per-block scan, 1 atomic/block)
__global__ __launch_bounds__(256) void alloc_k(const int* __restrict__ degi,
                                               float* dinv, int* rowptr, int* ecnt){
    __shared__ int sb[256];
    __shared__ int bbase;
    int t = threadIdx.x;
    int i = blockIdx.x*256 + t;
    int v = (i < NND) ? degi[i] : 0;
    sb[t] = v;
    __syncthreads();
    for (int off = 1; off < 256; off <<= 1){
        int x = 0;
        if (t >= off) x = sb[t - off];
        __syncthreads();
        sb[t] += x;
        __syncthreads();
    }
    if (t == 255) bbase = atomicAdd(ecnt, sb[255]);
    __syncthreads();
    if (i < NND){
        rowptr[i] = bbase + sb[t] - v;
        dinv[i] = 1.f/sqrtf((float)(degi[i] + 1));
    }
}

__global__ void fill_k(const int* __restrict__ ei, const int* __restrict__ rowptr,
                       int* cursor, int* adj){
    int i = blockIdx.x*256 + threadIdx.x;
    if (i < EE){
        int d = ei[EE + i];
        int s = ei[i];
        int p = atomicAdd(&cursor[d], 1);
        adj[rowptr[d] + p] = s;
    }
}

// token @ W1 partial sums; grid (2, 64) -> 128 blocks
__global__ __launch_bounds__(512) void tok_k(const float* __restrict__ posT,
        const float* __restrict__ negT,
        const float* __restrict__ sW1, const float* __restrict__ tW1,
        float* ptW, float* ntW){
    int b = blockIdx.x; int chunk = blockIdx.y; int j = threadIdx.x;
    const float* tok = b ? negT : posT;
    const float* Wm  = b ? tW1  : sW1;
    float acc = 0.f;
    int d0 = chunk * 47, d1 = d0 + 47; if (d1 > DD) d1 = DD;
    for (int d = d0; d < d1; ++d) acc += tok[d] * Wm[(long)d*HH + j];
    atomicAdd(&((b ? ntW : ptW)[j]), acc);
}

// ---------------- casts for MFMA path ----------------

__global__ __launch_bounds__(256) void cast_pad_x_k(const float* __restrict__ x,
                                                    unsigned short* __restrict__ xb){
    long idx = (long)blockIdx.x*256 + threadIdx.x;
    if (idx >= (long)MP*(KP/8)) return;
    int row = (int)(idx / (KP/8));
    int g   = (int)(idx % (KP/8));
    unsigned short o[8] = {0,0,0,0,0,0,0,0};
    if (row < NND && g < DD/8){
        const float* src = x + (long)row*DD + g*8;
        float4 a = *(const float4*)(src);
        float4 b = *(const float4*)(src + 4);
        o[0]=f2b(a.x); o[1]=f2b(a.y); o[2]=f2b(a.z); o[3]=f2b(a.w);
        o[4]=f2b(b.x); o[5]=f2b(b.y); o[6]=f2b(b.z); o[7]=f2b(b.w);
    }
    *(uint4*)(xb + (long)row*KP + g*8) = *(const uint4*)o;
}

// batched transpose-cast: out[c*OS + r] = bf16(in[r*C + c]), zero-fill r in [R,OS)
struct TBatch {
    const float* in[10];
    unsigned short* out[10];
    int R[10], C[10], OS[10];
    int t0[11];
};

__global__ void transbatch_k(TBatch tb){
    __shared__ unsigned short tile[32][33];
    int b = blockIdx.x;
    int d = 0;
    while (d < 9 && b >= tb.t0[d+1]) d++;
    const float* in = tb.in[d];
    unsigned short* out = tb.out[d];
    int R = tb.R[d], C = tb.C[d], OS = tb.OS[d];
    int lt = b - tb.t0[d];
    int Ctiles = (C + 31) >> 5;
    int rt = lt / Ctiles, ct = lt % Ctiles;
    int rb = rt*32, cb = ct*32;
    int tx = threadIdx.x, ty = threadIdx.y; // (32,8)
    for (int i = ty; i < 32; i += 8){
        int r = rb + i, c = cb + tx;
        tile[i][tx] = (r < R && c < C) ? f2b(in[(long)r*C + c]) : (unsigned short)0;
    }
    __syncthreads();
    for (int i = ty; i < 32; i += 8){
        int c = cb + i, r = rb + tx;
        if (c < C && r < OS) out[(long)c*OS + r] = (r < R) ? tile[tx][i] : (unsigned short)0;
    }
}

// ---------------- 320x128 MFMA GEMM, 256 blocks (1/CU), 2-barrier tiles --------
// (REVERTED to round-5 structure: round-6's frag-read pipeline raised VGPR
//  92->128 and spilled — WRITE_SIZE +1.5MB, dur +3us. This version: 74.4us.)
// A: MP x KP bf16, Bg: NW x KP bf16 (row = output col). C guarded to M rows.
// A triple-buffered (3 x 40 KiB), B double-buffered (2 x 16 KiB) = 152 KiB LDS.
// Per K-tile: [18 frag ds_reads + 4 A gl_lds][16 MFMA mt0-1] BAR_b
//             [1 A + 2 B gl_lds][24 MFMA mt2-4] vmcnt(7) BAR_c.

#define LDA(PB, MT, KS) (*(const bf16x8*)&As[(PB) + (KS)*AH_STR + a_off + (MT)*512])
#define LDB(PB, NT, KS) (*(const bf16x8*)&Bs[(PB) + (KS)*BH_STR + b_off + (NT)*512])

#define STG_A(KT, PDST, P) gl_lds16(asrc[P] + ((KT)<<6), &As[(PDST) + adst[P]])
#define STG_B(KT, PDST, Q) gl_lds16(bsrc[Q] + ((KT)<<6), &Bs[(PDST) + bdst[Q]])

#define GATE7 asm volatile("s_waitcnt vmcnt(7)" ::: "memory")
#define GATE0 asm volatile("s_waitcnt vmcnt(0)" ::: "memory")
#define NOOPS ((void)0)
#define AFENCE asm volatile("" ::: "memory")
#define BARR  { AFENCE; __builtin_amdgcn_s_barrier(); AFENCE; }

#define TILE_BODY(S1_STMT, S2_STMT, GATE_STMT) {                                  \
    bf16x8 af_[5][2], bf_[4][2];                                                  \
    _Pragma("unroll") for (int nt = 0; nt < 4; ++nt){                             \
        bf_[nt][0] = LDB(pB, nt, 0); bf_[nt][1] = LDB(pB, nt, 1); }               \
    _Pragma("unroll") for (int mt = 0; mt < 5; ++mt){                             \
        af_[mt][0] = LDA(pA, mt, 0); af_[mt][1] = LDA(pA, mt, 1); }               \
    S1_STMT;                                                                      \
    __builtin_amdgcn_s_setprio(1);                                                \
    _Pragma("unroll") for (int ks = 0; ks < 2; ++ks)                              \
      _Pragma("unroll") for (int nt = 0; nt < 4; ++nt)                            \
        _Pragma("unroll") for (int mt = 0; mt < 2; ++mt)                          \
          acc[mt][nt] = __builtin_amdgcn_mfma_f32_16x16x32_bf16(af_[mt][ks], bf_[nt][ks], acc[mt][nt], 0,0,0); \
    __builtin_amdgcn_s_setprio(0);                                                \
    BARR;                                                                         \
    S2_STMT;                                                                      \
    __builtin_amdgcn_s_setprio(1);                                                \
    _Pragma("unroll") for (int ks = 0; ks < 2; ++ks)                              \
      _Pragma("unroll") for (int nt = 0; nt < 4; ++nt)                            \
        _Pragma("unroll") for (int mt = 2; mt < 5; ++mt)                          \
          acc[mt][nt] = __builtin_amdgcn_mfma_f32_16x16x32_bf16(af_[mt][ks], bf_[nt][ks], acc[mt][nt], 0,0,0); \
    __builtin_amdgcn_s_setprio(0);                                                \
    GATE_STMT;                                                                    \
    BARR;                                                                         \
}

__global__ __launch_bounds__(512, 2) void gemm320(
    const unsigned short* __restrict__ Ag,
    const unsigned short* __restrict__ Bg,
    unsigned short* __restrict__ C,
    int M, int Cstride)
{
    __shared__ __align__(1024) unsigned short As[3*AB_STR]; // 120 KiB
    __shared__ __align__(1024) unsigned short Bs[2*BB_STR]; //  32 KiB

    // bijective XCD-chunked swizzle (nwg = 256, 256 % 8 == 0)
    const int bid = blockIdx.x;
    const int swz = (bid & 7)*32 + (bid >> 3);
    const int m0 = (swz >> 3) * BMT;   // 32 m-tiles
    const int n0 = (swz & 7) * BNT;    // 8 n-tiles

    const int tid = threadIdx.x;
    const int w   = tid >> 6,  l = tid & 63;
    const int wm  = w >> 1,    wn = w & 1;      // 4(M) x 2(N) wave grid: 80x64/wave
    const int l16 = l & 15,    quad = l >> 4;

    // staging: lane l writes LDS row (g*16 + l>>2), physical chunk (l&3);
    // global source chunk pre-swizzled by row-bit3 = l bit5.
    const int schunk = (l & 3) ^ (((l >> 5) & 1) << 1);
    // reads: logical chunk 'quad' -> physical chunk quad ^ ((row>>3)&1)<<1
    const int rq8   = ((quad ^ (((l16 >> 3) & 1) << 1)) << 3);
    const int a_off = ((wm*80 + l16) << 5) + rq8;
    const int b_off = ((wn*64 + l16) << 5) + rq8;

    // per-wave staging source pointers / LDS dest offsets (static-indexed)
    const unsigned short* asrc[5]; int adst[5];
    #pragma unroll
    for (int p = 0; p < 5; ++p){
        int j = 5*w + p, kh = j/20, g = j - kh*20;
        asrc[p] = Ag + (long)(m0 + g*16 + (l >> 2))*KP + (kh << 5) + (schunk << 3);
        adst[p] = kh*AH_STR + g*512;
    }
    const unsigned short* bsrc[2]; int bdst[2];
    #pragma unroll
    for (int q = 0; q < 2; ++q){
        int j = 2*w + q, kh = j >> 3, g = j & 7;
        bsrc[q] = Bg + (long)(n0 + g*16 + (l >> 2))*KP + (kh << 5) + (schunk << 3);
        bdst[q] = kh*BH_STR + g*512;
    }

    f32x4 acc[5][4];
    #pragma unroll
    for (int i = 0; i < 5; ++i)
        #pragma unroll
        for (int j = 0; j < 4; ++j)
            #pragma unroll
            for (int r = 0; r < 4; ++r) acc[i][j][r] = 0.f;

    // prologue: A(0),B(0)->buf0 [7], A(1),B(1)->buf1 [7]; drain tile-0's 7 only.
    #pragma unroll
    for (int p = 0; p < 5; ++p) STG_A(0, 0, p);
    #pragma unroll
    for (int q = 0; q < 2; ++q) STG_B(0, 0, q);
    #pragma unroll
    for (int p = 0; p < 5; ++p) STG_A(1, AB_STR, p);
    #pragma unroll
    for (int q = 0; q < 2; ++q) STG_B(1, BB_STR, q);
    GATE7;
    BARR;

    int ab = 0, bb = 0;   // buf of tile t: ab = t%3, bb = t&1
    #pragma unroll 1
    for (int t = 0; t < KTILES-2; ++t){
        const int pA  = ab*AB_STR;
        const int pB  = bb*BB_STR;                   // B(t) buf == B(t+2) dest buf
        const int ab2 = (ab == 0) ? 2 : ab - 1;      // (t+2)%3
        const int pA2 = ab2*AB_STR;
        TILE_BODY({ STG_A(t+2,pA2,0); STG_A(t+2,pA2,1); STG_A(t+2,pA2,2); STG_A(t+2,pA2,3); },
                  { STG_A(t+2,pA2,4); STG_B(t+2,pB,0); STG_B(t+2,pB,1); },
                  GATE7)
        ab = (ab == 2) ? 0 : ab + 1;
        bb ^= 1;
    }
    // peeled tile KTILES-2: no staging; full drain (tile-45's loads -> tile-47 data)
    {
        const int pA = ab*AB_STR, pB = bb*BB_STR;
        TILE_BODY(NOOPS, NOOPS, GATE0)
        ab = (ab == 2) ? 0 : ab + 1;
        bb ^= 1;
    }
    // peeled tile KTILES-1: no staging, no gate
    {
        const int pA = ab*AB_STR, pB = bb*BB_STR;
        TILE_BODY(NOOPS, NOOPS, NOOPS)
    }

    // epilogue: C/D layout col=lane&15, row=quad*4+reg
    #pragma unroll
    for (int mt = 0; mt < 5; ++mt){
        const int rowb = m0 + wm*80 + mt*16 + quad*4;
        #pragma unroll
        for (int nt = 0; nt < 4; ++nt){
            const int col = n0 + wn*64 + nt*16 + l16;
            #pragma unroll
            for (int r = 0; r < 4; ++r){
                const int row = rowb + r;
                if (row < M) C[(long)row*Cstride + col] = f2b(acc[mt][nt][r]);
            }
        }
    }
}

// ---------------- 64x64 MFMA GEMM: C = A[ridx?] @ BT^T (+epi) ----------------
// A: MxK bf16, BT: NnxK bf16, K % 32 == 0. epi: 0 none, 1 +bias, 2 +bias+prelu.
// obf: output bf16 (else f32). ridx: optional A row gather.
__device__ __forceinline__ void gemm_bt_body(
    const unsigned short* __restrict__ A,
    const unsigned short* __restrict__ BT,
    void* __restrict__ Cv,
    int M, int Nn, int K, int Cstride,
    const float* __restrict__ bias,
    const float* __restrict__ alpha,
    int epi, const int* __restrict__ ridx, int obf)
{
    __shared__ __align__(16) unsigned short As[64*40];
    __shared__ __align__(16) unsigned short Bs[64*40];
    const int m0 = blockIdx.y*64, n0 = blockIdx.x*64;
    const int t = threadIdx.x;
    const int lrow = t >> 2, lk = (t & 3) * 8;
    const int wave = t >> 6, lane = t & 63;
    const int quad = lane >> 4, l16 = lane & 15;
    f32x4 acc[4];
    #pragma unroll
    for (int i = 0; i < 4; i++)
        for (int j = 0; j < 4; j++) acc[i][j] = 0.f;

    const bool arv = (m0 + lrow) < M;
    const bool brv = (n0 + lrow) < Nn;
    long arow = 0;
    if (arv) arow = ridx ? (long)ridx[m0 + lrow] : (long)(m0 + lrow);
    const long arowbase = arow * K;
    const long browbase = (long)(n0 + lrow) * K;

    for (int k0 = 0; k0 < K; k0 += 32){
        int gk = k0 + lk;
        uint4 av = {0u,0u,0u,0u};
        uint4 bv = {0u,0u,0u,0u};
        if (arv) av = *(const uint4*)(A + arowbase + gk);
        if (brv) bv = *(const uint4*)(BT + browbase + gk);
        *(uint4*)(&As[lrow*40 + lk]) = av;
        *(uint4*)(&Bs[lrow*40 + lk]) = bv;
        __syncthreads();
        bf16x8 af = *(const bf16x8*)(&As[(wave*16 + l16)*40 + quad*8]);
        #pragma unroll
        for (int nt = 0; nt < 4; nt++){
            bf16x8 bfr = *(const bf16x8*)(&Bs[(nt*16 + l16)*40 + quad*8]);
            acc[nt] = __builtin_amdgcn_mfma_f32_16x16x32_bf16(af, bfr, acc[nt], 0, 0, 0);
        }
        __syncthreads();
    }

    const int rowb = m0 + wave*16 + quad*4;
    float aval = (epi == 2) ? alpha[0] : 0.f;
    #pragma unroll
    for (int nt = 0; nt < 4; nt++){
        int col = n0 + nt*16 + l16;
        if (col >= Nn) continue;
        float bvv = epi ? bias[col] : 0.f;
        #pragma unroll
        for (int r = 0; r < 4; r++){
            int row = rowb + r;
            if (row < M){
                float v = acc[nt][r] + bvv;
                if (epi == 2 && v < 0.f) v *= aval;
                if (obf) ((unsigned short*)Cv)[(long)row*Cstride + col] = f2b(v);
                else     ((float*)Cv)[(long)row*Cstride + col] = v;
            }
        }
    }
}

__global__ __launch_bounds__(256) void gemm_bt_ex(
    const unsigned short* __restrict__ A,
    const unsigned short* __restrict__ BT,
    void* __restrict__ Cv,
    int M, int Nn, int K, int Cstride,
    const float* __restrict__ bias,
    const float* __restrict__ alpha,
    int epi, const int* __restrict__ ridx, int obf)
{
    gemm_bt_body(A, BT, Cv, M, Nn, K, Cstride, bias, alpha, epi, ridx, obf);
}

// z-batched pair variant: blockIdx.z selects the (A,B,C,bias,alpha) set.
__global__ __launch_bounds__(256) void gemm_bt2(
    const unsigned short* __restrict__ A0, const unsigned short* __restrict__ A1,
    const unsigned short* __restrict__ B0, const unsigned short* __restrict__ B1,
    void* __restrict__ C0, void* __restrict__ C1,
    int M, int Nn, int K, int Cstride,
    const float* __restrict__ bias0, const float* __restrict__ bias1,
    const float* __restrict__ al0, const float* __restrict__ al1,
    int epi, const int* __restrict__ ridx, int obf)
{
    if (blockIdx.z == 0)
        gemm_bt_body(A0, B0, C0, M, Nn, K, Cstride, bias0, al0, epi, ridx, obf);
    else
        gemm_bt_body(A1, B1, C1, M, Nn, K, Cstride, bias1, al1, epi, ridx, obf);
}

// 3-way fused launch: z=0/1 = projection-H (pos/neg, gathered rows, prelu),
// z=2 = decoder pre-matmul recPre (independent of both). Ragged grid with
// early-exit guards; launch (4, 157, 3).
__global__ __launch_bounds__(256) void gemm_bt3(
    const unsigned short* __restrict__ repP, const unsigned short* __restrict__ repN,
    const unsigned short* __restrict__ pW1T, const unsigned short* __restrict__ tpW1T,
    const unsigned short* __restrict__ e2dWT,
    unsigned short* __restrict__ posH, unsigned short* __restrict__ negH,
    unsigned short* __restrict__ recPre,
    const float* __restrict__ pb1, const float* __restrict__ tpb1,
    const float* __restrict__ pa, const float* __restrict__ tpa,
    const int* __restrict__ perm)
{
    int z = blockIdx.z;
    if (z == 0){
        if (blockIdx.y < 47)
            gemm_bt_body(repP, pW1T, posH, NM, PP, LL, PP, pb1, pa, 2, perm, 1);
    } else if (z == 1){
        if (blockIdx.y < 47)
            gemm_bt_body(repN, tpW1T, negH, NM, PP, LL, PP, tpb1, tpa, 2, perm, 1);
    } else {
        if (blockIdx.x < 2)
            gemm_bt_body(repP, e2dWT, recPre, NND, LL, LL, LL, nullptr, nullptr, 0, nullptr, 1);
    }
}

// ---------------- fused GCN layer-1 aggregation (pos + neg), bf16 I/O ----------------
// warps 0-1: pos half (XW cols [0,512)); warps 2-3: neg half (cols [512,1024) of
// gathered negsrc rows). uint2 loads (4 cols/thread). flag branches are
// block-uniform -> masked neg gathers are SKIPPED entirely (~30% of edges).

__global__ __launch_bounds__(256) void agg1_k(const unsigned short* __restrict__ XW,
    const float* __restrict__ ptW, const float* __restrict__ ntW,
    const int* __restrict__ flag, const int* __restrict__ negsrc,
    const float* __restrict__ dinv, const int* __restrict__ rowptr,
    const int* __restrict__ degi, const int* __restrict__ adj,
    const float* __restrict__ sb1, const float* __restrict__ sav,
    const float* __restrict__ tb1, const float* __restrict__ tav,
    unsigned short* __restrict__ H1p, unsigned short* __restrict__ H1n)
{
    int i = blockIdx.x; int t = threadIdx.x;
    int half = t >> 7;          // 0 = pos, 1 = neg
    int c = (t & 127) * 4;      // cols c..c+3 in [0,512)
    float di = dinv[i];
    int rs = rowptr[i], re = rs + degi[i];
    int fi = flag[i];
    float a0, a1, a2, a3;

    if (half == 0){
        float p0 = ptW[c], p1 = ptW[c+1], p2 = ptW[c+2], p3 = ptW[c+3];
        uint2 v = *(const uint2*)(XW + (long)i*1024 + c);
        float2 va = bpair(v.x), vb = bpair(v.y);
        float ffi = fi ? 1.f : 0.f;
        a0 = (va.x + ffi*p0)*di; a1 = (va.y + ffi*p1)*di;
        a2 = (vb.x + ffi*p2)*di; a3 = (vb.y + ffi*p3)*di;
        for (int e = rs; e < re; ++e){
            int s = adj[e]; float ds = dinv[s];
            float ffs = flag[s] ? 1.f : 0.f;
            uint2 w = *(const uint2*)(XW + (long)s*1024 + c);
            float2 wa = bpair(w.x), wb = bpair(w.y);
            a0 += (wa.x + ffs*p0)*ds; a1 += (wa.y + ffs*p1)*ds;
            a2 += (wb.x + ffs*p2)*ds; a3 += (wb.y + ffs*p3)*ds;
        }
        float sa_ = sav[0];
        float v0 = di*a0 + sb1[c];   if (v0 < 0.f) v0 *= sa_;
        float v1 = di*a1 + sb1[c+1]; if (v1 < 0.f) v1 *= sa_;
        float v2 = di*a2 + sb1[c+2]; if (v2 < 0.f) v2 *= sa_;
        float v3 = di*a3 + sb1[c+3]; if (v3 < 0.f) v3 *= sa_;
        uint2 o; o.x = packb(v0, v1); o.y = packb(v2, v3);
        *(uint2*)(H1p + (long)i*512 + c) = o;
    } else {
        float n0 = ntW[c], n1 = ntW[c+1], n2 = ntW[c+2], n3 = ntW[c+3];
        if (fi){ a0 = n0*di; a1 = n1*di; a2 = n2*di; a3 = n3*di; }
        else {
            int nsi = negsrc[i];
            uint2 v = *(const uint2*)(XW + (long)nsi*1024 + 512 + c);
            float2 va = bpair(v.x), vb = bpair(v.y);
            a0 = va.x*di; a1 = va.y*di; a2 = vb.x*di; a3 = vb.y*di;
        }
        for (int e = rs; e < re; ++e){
            int s = adj[e]; float ds = dinv[s];
            if (flag[s]){ a0 += n0*ds; a1 += n1*ds; a2 += n2*ds; a3 += n3*ds; }
            else {
                int ns = negsrc[s];
                uint2 w = *(const uint2*)(XW + (long)ns*1024 + 512 + c);
                float2 wa = bpair(w.x), wb = bpair(w.y);
                a0 += wa.x*ds; a1 += wa.y*ds; a2 += wb.x*ds; a3 += wb.y*ds;
            }
        }
        float ta_ = tav[0];
        float v0 = di*a0 + tb1[c];   if (v0 < 0.f) v0 *= ta_;
        float v1 = di*a1 + tb1[c+1]; if (v1 < 0.f) v1 *= ta_;
        float v2 = di*a2 + tb1[c+2]; if (v2 < 0.f) v2 *= ta_;
        float v3 = di*a3 + tb1[c+3]; if (v3 < 0.f) v3 *= ta_;
        uint2 o; o.x = packb(v0, v1); o.y = packb(v2, v3);
        *(uint2*)(H1n + (long)i*512 + c) = o;
    }
}

// fused pos/neg second-layer aggregation: wave 0 = pos, wave 1 = neg (one block
// per node -> adj/dinv scalar loads shared via L1); uint loads (2 cols/thread).
__global__ __launch_bounds__(128) void agg128_k(
    const unsigned short* __restrict__ In0, const unsigned short* __restrict__ In1,
    const float* __restrict__ dinv, const int* __restrict__ rowptr,
    const int* __restrict__ degi, const int* __restrict__ adj,
    const float* __restrict__ b20, const float* __restrict__ b21,
    const float* __restrict__ a20, const float* __restrict__ a21,
    unsigned short* __restrict__ Out0, unsigned short* __restrict__ Out1)
{
    int i = blockIdx.x, t = threadIdx.x;
    int h = t >> 6;
    int c = (t & 63) * 2;
    const unsigned short* In = h ? In1 : In0;
    const float* b2 = h ? b21 : b20;
    const float* a2 = h ? a21 : a20;
    unsigned short* Out = h ? Out1 : Out0;
    float di = dinv[i];
    int rs = rowptr[i], re = rs + degi[i];
    float2 sv = bpair(*(const unsigned int*)(In + (long)i*128 + c));
    float acc0 = sv.x * di, acc1 = sv.y * di;
    for (int e = rs; e < re; ++e){
        int s = adj[e]; float ds = dinv[s];
        float2 w = bpair(*(const unsigned int*)(In + (long)s*128 + c));
        acc0 += w.x * ds; acc1 += w.y * ds;
    }
    float a = a2[0];
    float v0 = di*acc0 + b2[c];   if (v0 < 0.f) v0 *= a;
    float v1 = di*acc1 + b2[c+1]; if (v1 < 0.f) v1 *= a;
    *(unsigned int*)(Out + (long)i*128 + c) = packb(v0, v1);
}

// decoder aggregation over unmasked neighbors; uint loads, masked gathers skipped.
__global__ __launch_bounds__(64) void aggrec_k(const unsigned short* __restrict__ recPre,
    const float* __restrict__ dinv, const int* __restrict__ rowptr,
    const int* __restrict__ degi, const int* __restrict__ adj,
    const int* __restrict__ flag, const int* __restrict__ perm,
    unsigned short* __restrict__ recAgg)
{
    int b = blockIdx.x, t = threadIdx.x;
    int c = t * 2;
    int i = perm[b];
    float di = dinv[i];
    int rs = rowptr[i], re = rs + degi[i];
    float acc0 = 0.f, acc1 = 0.f; // self loop: i is a mask node -> rec row zeroed
    for (int e = rs; e < re; ++e){
        int s = adj[e];
        if (!flag[s]){
            float ds = dinv[s];
            float2 w = bpair(*(const unsigned int*)(recPre + (long)s*128 + c));
            acc0 += w.x * ds; acc1 += w.y * ds;
        }
    }
    *(unsigned int*)(recAgg + (long)b*128 + c) = packb(di*acc0, di*acc1);
}

// ---------------- DGI head ----------------

__global__ __launch_bounds__(128) void meanp_k(const float* __restrict__ posZ,
                                               float* svecraw){
    int j = threadIdx.x;
    int r0 = blockIdx.x*64, r1 = r0 + 64; if (r1 > NM) r1 = NM;
    float s = 0.f;
    for (int r = r0; r < r1; ++r) s += posZ[(long)r*128 + j];
    atomicAdd(&svecraw[j], s);
}

__global__ void ws_k(const float* __restrict__ dgiW, const float* __restrict__ svecraw,
                     float* wsv){
    __shared__ float s[128];
    int i = threadIdx.x; // 128
    s[i] = 1.f/(1.f + expf(-svecraw[i]/(float)NM));
    __syncthreads();
    float a = 0.f;
    for (int j = 0; j < 128; ++j) a += dgiW[i*128 + j] * s[j];
    wsv[i] = a;
}

// grid-stride rows; per-wave accumulate; 2 atomics per block.
__global__ __launch_bounds__(256) void dgi_k(const float* __restrict__ posZ,
    const float* __restrict__ negZ, const float* __restrict__ wsv, float* scal){
    __shared__ float sp[4], sn[4];
    int wid = threadIdx.x >> 6, lane = threadIdx.x & 63;
    float w0 = wsv[lane], w1 = wsv[64 + lane];
    float accp = 0.f, accn = 0.f;
    for (int row = blockIdx.x*4 + wid; row < 2*NM; row += gridDim.x*4){
        const float* Z = (row < NM) ? posZ : negZ;
        int r = (row < NM) ? row : row - NM;
        float v = Z[(long)r*128 + lane] * w0 + Z[(long)r*128 + 64 + lane] * w1;
        for (int off = 32; off; off >>= 1) v += __shfl_down(v, off, 64);
        if (lane == 0){
            float d = 1.f/(1.f + expf(-v));
            if (row < NM) accp += logf(d + 1e-15f);
            else          accn += logf(1.f - d + 1e-15f);
        }
    }
    if (lane == 0){ sp[wid] = accp; sn[wid] = accn; }
    __syncthreads();
    if (threadIdx.x == 0){
        atomicAdd(&scal[0], sp[0]+sp[1]+sp[2]+sp[3]);
        atomicAdd(&scal[1], sn[0]+sn[1]+sn[2]+sn[3]);
    }
}

// ---------------- cosine feature loss ----------------
// 8 cols/thread: float4 x reads, uint4 recMask reads (was 2B scalar).

__global__ __launch_bounds__(256) void cos_k(const float* __restrict__ x,
    const unsigned short* __restrict__ recMask, const int* __restrict__ perm,
    float* scal){
    int b = blockIdx.x, t = threadIdx.x;
    long xi = (long)perm[b]*DD;
    long ri = (long)b*DD;
    float dot = 0.f, nx = 0.f, nr = 0.f;
    for (int d0 = t*8; d0 < DD; d0 += 2048){
        float4 xa = *(const float4*)(x + xi + d0);
        float4 xb2 = *(const float4*)(x + xi + d0 + 4);
        uint4 rv = *(const uint4*)(recMask + ri + d0);
        float2 r0 = bpair(rv.x), r1 = bpair(rv.y), r2 = bpair(rv.z), r3 = bpair(rv.w);
        dot += xa.x*r0.x + xa.y*r0.y + xa.z*r1.x + xa.w*r1.y
             + xb2.x*r2.x + xb2.y*r2.y + xb2.z*r3.x + xb2.w*r3.y;
        nx  += xa.x*xa.x + xa.y*xa.y + xa.z*xa.z + xa.w*xa.w
             + xb2.x*xb2.x + xb2.y*xb2.y + xb2.z*xb2.z + xb2.w*xb2.w;
        nr  += r0.x*r0.x + r0.y*r0.y + r1.x*r1.x + r1.y*r1.y
             + r2.x*r2.x + r2.y*r2.y + r3.x*r3.x + r3.y*r3.y;
    }
    for (int off = 32; off; off >>= 1){
        dot += __shfl_down(dot, off, 64);
        nx  += __shfl_down(nx,  off, 64);
        nr  += __shfl_down(nr,  off, 64);
    }
    __shared__ float sd[4], sx[4], sr[4];
    int w = t >> 6, lane = t & 63;
    if (lane == 0){ sd[w] = dot; sx[w] = nx; sr[w] = nr; }
    __syncthreads();
    if (t == 0){
        float Dv = sd[0]+sd[1]+sd[2]+sd[3];
        float Xv = sx[0]+sx[1]+sx[2]+sx[3];
        float Rv = sr[0]+sr[1]+sr[2]+sr[3];
        float c = Dv/(fmaxf(sqrtf(Xv),1e-12f)*fmaxf(sqrtf(Rv),1e-12f));
        float e = 1.f - c;
        atomicAdd(&scal[16 + (b & 63)], e*e);   // 64-way spread -> ~47 per slot
    }
}

__global__ void fin_k(const float* __restrict__ scal, float* out){
    float fs = 0.f;
    for (int i = 0; i < 64; ++i) fs += scal[16 + i];
    float feat = fs/(float)NM;
    float dgi  = -(scal[0]/(float)NM) - (scal[1]/(float)NM);
    out[0] = feat;
    out[1] = dgi;
}

// ---------------- launch ----------------

extern "C" void kernel_launch(void* const* d_in, const int* in_sizes, int n_in,
                              void* d_out, int out_size, void* d_ws, size_t ws_size,
                              hipStream_t stream) {
    (void)in_sizes; (void)n_in; (void)out_size; (void)d_ws; (void)ws_size;
    const float* x  = (const float*)d_in[0];
    const int* ei   = (const int*)d_in[1];
    const int* perm = (const int*)d_in[2];
    const int* shuf = (const int*)d_in[3];
    const float* sW1 = (const float*)d_in[4];
    const float* sb1 = (const float*)d_in[5];
    const float* sa  = (const float*)d_in[6];
    const float* sW2 = (const float*)d_in[7];
    const float* sb2 = (const float*)d_in[8];
    const float* tW1 = (const float*)d_in[9];
    const float* tb1 = (const float*)d_in[10];
    const float* ta  = (const float*)d_in[11];
    const float* tW2 = (const float*)d_in[12];
    const float* tb2 = (const float*)d_in[13];
    const float* pW1 = (const float*)d_in[14];
    const float* pb1 = (const float*)d_in[15];
    const float* pa  = (const float*)d_in[16];
    const float* pW2 = (const float*)d_in[17];
    const float* pb2 = (const float*)d_in[18];
    const float* tpW1 = (const float*)d_in[19];
    const float* tpb1 = (const float*)d_in[20];
    const float* tpa  = (const float*)d_in[21];
    const float* tpW2 = (const float*)d_in[22];
    const float* tpb2 = (const float*)d_in[23];
    const float* dgiW = (const float*)d_in[24];
    const float* posT = (const float*)d_in[25];
    const float* negT = (const float*)d_in[26];
    const float* e2dW = (const float*)d_in[27];
    const float* dW   = (const float*)d_in[28];
    const float* db   = (const float*)d_in[29];
    float* out = (float*)d_out;

    void* wsp = nullptr;
    hipGetSymbolAddress(&wsp, HIP_SYMBOL(g_ws));
    char* base = (char*)wsp;
    size_t off = 0;
    auto alloc = [&](size_t b){ size_t o = off; off = (off + b + 255) & ~(size_t)255; return o; };

    float* dinv    = (float*)(base + alloc(NND*4));
    int* degi      = (int*)  (base + alloc(NND*4));
    int* rowptr    = (int*)  (base + alloc(NND*4));
    int* cursor    = (int*)  (base + alloc(NND*4));
    int* adj       = (int*)  (base + alloc(EE*4));
    int* flag      = (int*)  (base + alloc(NND*4));
    int* negsrc    = (int*)  (base + alloc(NND*4));
    int* ecnt      = (int*)  (base + alloc(16*4));
    float* ptW     = (float*)(base + alloc(HH*4));
    float* ntW     = (float*)(base + alloc(HH*4));
    float* svecraw = (float*)(base + alloc(128*4));
    float* wsv     = (float*)(base + alloc(128*4));
    float* scal    = (float*)(base + alloc(80*4));

    unsigned short* xb    = (unsigned short*)(base + alloc((size_t)MP*KP*2));
    unsigned short* W1T   = (unsigned short*)(base + alloc((size_t)NW*KP*2));
    unsigned short* sW2T  = (unsigned short*)(base + alloc((size_t)LL*HH*2));
    unsigned short* tW2T  = (unsigned short*)(base + alloc((size_t)LL*HH*2));
    unsigned short* pW1T  = (unsigned short*)(base + alloc((size_t)PP*LL*2));
    unsigned short* pW2T  = (unsigned short*)(base + alloc((size_t)LL*PP*2));
    unsigned short* tpW1T = (unsigned short*)(base + alloc((size_t)PP*LL*2));
    unsigned short* tpW2T = (unsigned short*)(base + alloc((size_t)LL*PP*2));
    unsigned short* e2dWT = (unsigned short*)(base + alloc((size_t)LL*LL*2));
    unsigned short* dWT   = (unsigned short*)(base + alloc((size_t)DD*LL*2));

    unsigned short* XW      = (unsigned short*)(base + alloc((size_t)NND*1024*2));
    unsigned short* H1p     = (unsigned short*)(base + alloc((size_t)NND*512*2));
    unsigned short* H1n     = (unsigned short*)(base + alloc((size_t)NND*512*2));
    unsigned short* M2p     = (unsigned short*)(base + alloc((size_t)NND*128*2));
    unsigned short* M2n     = (unsigned short*)(base + alloc((size_t)NND*128*2));
    unsigned short* repP    = (unsigned short*)(base + alloc((size_t)NND*128*2));
    unsigned short* repN    = (unsigned short*)(base + alloc((size_t)NND*128*2));
    unsigned short* posH    = (unsigned short*)(base + alloc((size_t)NM*256*2));
    unsigned short* negH    = (unsigned short*)(base + alloc((size_t)NM*256*2));
    float* posZ             = (float*)(base + alloc((size_t)NM*128*4));
    float* negZ             = (float*)(base + alloc((size_t)NM*128*4));
    unsigned short* recPre  = (unsigned short*)(base + alloc((size_t)NND*128*2));
    unsigned short* recAgg  = (unsigned short*)(base + alloc((size_t)NM*128*2));
    unsigned short* recMask = (unsigned short*)(base + alloc((size_t)NM*DD*2));

    // ---- graph build (scan-free) ----
    init_k<<<(NND+255)/256, 256, 0, stream>>>(degi, cursor, scal, ptW, ntW, svecraw, ecnt);
    build_k<<<(EE+255)/256, 256, 0, stream>>>(ei, perm, shuf, degi, flag, negsrc);
    alloc_k<<<(NND+255)/256, 256, 0, stream>>>(degi, dinv, rowptr, ecnt);
    fill_k<<<(EE+255)/256, 256, 0, stream>>>(ei, rowptr, cursor, adj);
    tok_k<<<dim3(2,64), 512, 0, stream>>>(posT, negT, sW1, tW1, ptW, ntW);

    // ---- bf16 staging ----
    cast_pad_x_k<<<(int)(((long)MP*(KP/8) + 255)/256), 256, 0, stream>>>(x, xb);
    {
        TBatch tb;
        const float* ins[10] = {sW1, tW1, sW2, tW2, pW1, pW2, tpW1, tpW2, e2dW, dW};
        unsigned short* outs[10] = {W1T, W1T + (size_t)HH*KP, sW2T, tW2T, pW1T, pW2T,
                                    tpW1T, tpW2T, e2dWT, dWT};
        int Rs[10]  = {DD, DD, HH, HH, LL, PP, LL, PP, LL, LL};
        int Cs[10]  = {HH, HH, LL, LL, PP, LL, PP, LL, LL, DD};
        int OSs[10] = {KP, KP, HH, HH, LL, PP, LL, PP, LL, LL};
        int cum = 0;
        for (int d = 0; d < 10; d++){
            tb.in[d] = ins[d]; tb.out[d] = outs[d];
            tb.R[d] = Rs[d]; tb.C[d] = Cs[d]; tb.OS[d] = OSs[d];
            tb.t0[d] = cum;
            cum += (OSs[d]/32) * ((Cs[d] + 31)/32);
        }
        tb.t0[10] = cum;
        transbatch_k<<<cum, dim3(32,8), 0, stream>>>(tb);
    }

    // ---- encoder layer 1 (MFMA 320x128, 256 blocks) + fused aggregation ----
    gemm320<<<256, 512, 0, stream>>>(xb, W1T, XW, NND, 1024);
    agg1_k<<<NND, 256, 0, stream>>>(XW, ptW, ntW, flag, negsrc, dinv, rowptr, degi, adj,
                                    sb1, sa, tb1, ta, H1p, H1n);

    // ---- encoder layer 2 (MFMA, z-batched pair) + fused aggregation ----
    gemm_bt2<<<dim3(2,157,2), 256, 0, stream>>>(H1p, H1n, sW2T, tW2T, M2p, M2n,
                                                NND, LL, HH, LL,
                                                nullptr, nullptr, nullptr, nullptr,
                                                0, nullptr, 1);
    agg128_k<<<NND, 128, 0, stream>>>(M2p, M2n, dinv, rowptr, degi, adj,
                                      sb2, tb2, sa, ta, repP, repN);

    // ---- projections-H (pos+neg) + decoder recPre, one ragged z=3 launch ----
    gemm_bt3<<<dim3(4,157,3), 256, 0, stream>>>(repP, repN, pW1T, tpW1T, e2dWT,
                                                posH, negH, recPre,
                                                pb1, tpb1, pa, tpa, perm);
    gemm_bt2<<<dim3(2,47,2), 256, 0, stream>>>(posH, negH, pW2T, tpW2T, posZ, negZ,
                                               NM, LL, PP, LL,
                                               pb2, tpb2, nullptr, nullptr, 1, nullptr, 0);

    // ---- decoder aggregation + reconstruction ----
    aggrec_k<<<NM, 64, 0, stream>>>(recPre, dinv, rowptr, degi, adj, flag, perm, recAgg);
    gemm_bt_ex<<<dim3(47,47), 256, 0, stream>>>(recAgg, dWT, recMask, NM, DD, LL, DD,
                                                db, nullptr, 1, nullptr, 1);

    // ---- DGI loss ----
    meanp_k<<<47, 128, 0, stream>>>(posZ, svecraw);
    ws_k<<<1, 128, 0, stream>>>(dgiW, svecraw, wsv);
    dgi_k<<<128, 256, 0, stream>>>(posZ, negZ, wsv, scal);

    // ---- feature loss ----
    cos_k<<<NM, 256, 0, stream>>>(x, recMask, perm, scal);

    fin_k<<<1, 1, 0, stream>>>(scal, out);
}

// Round 8
// 457.381 us; speedup vs baseline: 1.1385x; 1.0866x over previous
//
#include <hip/hip_runtime.h>

#define NND 10000
#define EE  60000
#define DD  3000
#define HH  512
#define LL  128
#define PP  256
#define NM  3000

// padded dims for the big MFMA GEMM (no tail guards in hot loop)
#define KP  3072            // 48 * 64
#define MP  10240           // 32 * 320
#define NW  1024            // [sW1|tW1] fused width, 8*128
#define KTILES (KP/64)      // 48

// gemm320 tile geometry
#define BMT 320
#define BNT 128
#define AH_STR 10240        // elems per A k-half (320 rows x 32)
#define AB_STR 20480        // elems per A buf (2 k-halves)
#define BH_STR 4096         // elems per B k-half (128 rows x 32)
#define BB_STR 8192         // elems per B buf

typedef short bf16x8 __attribute__((ext_vector_type(8)));
typedef float f32x4 __attribute__((ext_vector_type(4)));

// All scratch lives in module BSS -> no dependency on harness ws_size.
__device__ __align__(256) char g_ws[(size_t)176 << 20];

__device__ __forceinline__ unsigned short f2b(float f){
    unsigned int x = __float_as_uint(f);
    unsigned int r = x + 0x7FFFu + ((x >> 16) & 1u);
    return (unsigned short)(r >> 16);
}
__device__ __forceinline__ float b2f(unsigned short u){
    return __uint_as_float(((unsigned int)u) << 16);
}
// uint holding 2 bf16 (low = col c, high = col c+1)
__device__ __forceinline__ float2 bpair(unsigned int u){
    float2 r;
    r.x = __uint_as_float(u << 16);
    r.y = __uint_as_float(u & 0xffff0000u);
    return r;
}
__device__ __forceinline__ unsigned int packb(float a, float b){
    return (unsigned int)f2b(a) | ((unsigned int)f2b(b) << 16);
}

__device__ __forceinline__ void gl_lds16(const void* g, void* l){
    __builtin_amdgcn_global_load_lds(
        (const __attribute__((address_space(1))) unsigned int*)g,
        (__attribute__((address_space(3))) unsigned int*)l, 16, 0, 0);
}

// ---------------- init / graph build ----------------

__global__ void init_k(int* degi, int* cursor, float* scal,
                       float* ptW, float* ntW, float* svecraw, int* ecnt){
    int i = blockIdx.x*256 + threadIdx.x;
    if (i < NND){ degi[i]=0; cursor[i]=0; }
    if (i < 80) scal[i]=0.f;           // [0]=dgi-pos [1]=dgi-neg [16..79]=cos slots
    if (i == 0) ecnt[0]=0;
    if (i < 128) svecraw[i]=0.f;
    if (i < HH){ ptW[i]=0.f; ntW[i]=0.f; }
}

// merged: degree count (i < EE) + mask flags (i < NND)
__global__ void build_k(const int* __restrict__ ei,
                        const int* __restrict__ perm, const int* __restrict__ shuf,
                        int* degi, int* flag, int* negsrc){
    int i = blockIdx.x*256 + threadIdx.x;
    if (i < EE) atomicAdd(&degi[ei[EE + i]], 1);
    if (i < NND){
        int p = perm[i];
        if (i < NM){ flag[p] = 1; negsrc[p] = -1; }
        else       { flag[p] = 0; negsrc[p] = perm[NM + shuf[i - NM]]; }
    }
}

// dinv + CSR segment allocation (order-free; per-block scan, 1 atomic/block)
__global__ __launch_bounds__(256) void alloc_k(const int* __restrict__ degi,
                                               float* dinv, int* rowptr, int* ecnt){
    __shared__ int sb[256];
    __shared__ int bbase;
    int t = threadIdx.x;
    int i = blockIdx.x*256 + t;
    int v = (i < NND) ? degi[i] : 0;
    sb[t] = v;
    __syncthreads();
    for (int off = 1; off < 256; off <<= 1){
        int x = 0;
        if (t >= off) x = sb[t - off];
        __syncthreads();
        sb[t] += x;
        __syncthreads();
    }
    if (t == 255) bbase = atomicAdd(ecnt, sb[255]);
    __syncthreads();
    if (i < NND){
        rowptr[i] = bbase + sb[t] - v;
        dinv[i] = 1.f/sqrtf((float)(degi[i] + 1));
    }
}

__global__ void fill_k(const int* __restrict__ ei, const int* __restrict__ rowptr,
                       int* cursor, int* adj){
    int i = blockIdx.x*256 + threadIdx.x;
    if (i < EE){
        int d = ei[EE + i];
        int s = ei[i];
        int p = atomicAdd(&cursor[d], 1);
        adj[rowptr[d] + p] = s;
    }
}

// ---------------- mega staging: cast_pad + transbatch + tok in ONE dispatch ----
// All three are input-only and mutually independent; blockIdx ranges select the
// role. Saves 2 dispatch gaps and hides the small trans/tok work in cast's tail.

struct TBatch {
    const float* in[10];
    unsigned short* out[10];
    int R[10], C[10], OS[10];
    int t0[11];
};

#define CASTB ((int)(((long)MP*(KP/8) + 255)/256))   // 15360

__global__ __launch_bounds__(256) void stage_k(TBatch tb,
    const float* __restrict__ x, unsigned short* __restrict__ xb,
    const float* __restrict__ posT, const float* __restrict__ negT,
    const float* __restrict__ sW1, const float* __restrict__ tW1,
    float* ptW, float* ntW)
{
    __shared__ unsigned short tile[32][33];
    int b = blockIdx.x;
    int t = threadIdx.x;
    if (b < CASTB){
        long idx = (long)b*256 + t;
        if (idx < (long)MP*(KP/8)){
            int row = (int)(idx / (KP/8));
            int g   = (int)(idx % (KP/8));
            unsigned short o[8] = {0,0,0,0,0,0,0,0};
            if (row < NND && g < DD/8){
                const float* src = x + (long)row*DD + g*8;
                float4 a = *(const float4*)(src);
                float4 bb = *(const float4*)(src + 4);
                o[0]=f2b(a.x); o[1]=f2b(a.y); o[2]=f2b(a.z); o[3]=f2b(a.w);
                o[4]=f2b(bb.x); o[5]=f2b(bb.y); o[6]=f2b(bb.z); o[7]=f2b(bb.w);
            }
            *(uint4*)(xb + (long)row*KP + g*8) = *(const uint4*)o;
        }
        return;
    }
    b -= CASTB;
    if (b < tb.t0[10]){
        // transpose-cast: out[c*OS + r] = bf16(in[r*C + c]), zero-fill r in [R,OS)
        int d = 0;
        while (d < 9 && b >= tb.t0[d+1]) d++;
        const float* in = tb.in[d];
        unsigned short* out = tb.out[d];
        int R = tb.R[d], C = tb.C[d], OS = tb.OS[d];
        int lt = b - tb.t0[d];
        int Ctiles = (C + 31) >> 5;
        int rt = lt / Ctiles, ct = lt % Ctiles;
        int rb = rt*32, cb = ct*32;
        int tx = t & 31, ty = t >> 5;   // (32,8)
        for (int i = ty; i < 32; i += 8){
            int r = rb + i, c = cb + tx;
            tile[i][tx] = (r < R && c < C) ? f2b(in[(long)r*C + c]) : (unsigned short)0;
        }
        __syncthreads();
        for (int i = ty; i < 32; i += 8){
            int c = cb + i, r = rb + tx;
            if (c < C && r < OS) out[(long)c*OS + r] = (r < R) ? tile[tx][i] : (unsigned short)0;
        }
        return;
    }
    b -= tb.t0[10];
    // token @ W1 partial sums: 256 sub-blocks (b&1 = pos/neg, b>>1 = row chunk)
    int tokb = b & 1, chunk = b >> 1;
    const float* tok = tokb ? negT : posT;
    const float* Wm  = tokb ? tW1 : sW1;
    float acc0 = 0.f, acc1 = 0.f;
    int d0 = chunk*24, d1 = d0 + 24; if (d1 > DD) d1 = DD;
    for (int d = d0; d < d1; ++d){
        float tv = tok[d];
        acc0 += tv * Wm[(long)d*HH + t];
        acc1 += tv * Wm[(long)d*HH + t + 256];
    }
    float* dst = tokb ? ntW : ptW;
    atomicAdd(&dst[t], acc0);
    atomicAdd(&dst[t+256], acc1);
}

// ---------------- 320x128 MFMA GEMM, 256 blocks (1/CU), 2-barrier tiles --------
// (round-5 structure, 74.4us / VGPR 92 — do not touch; round-6's pipeline
//  attempt spilled. See journal.)
// A: MP x KP bf16, Bg: NW x KP bf16 (row = output col). C guarded to M rows.
// A triple-buffered (3 x 40 KiB), B double-buffered (2 x 16 KiB) = 152 KiB LDS.
// Per K-tile: [18 frag ds_reads + 4 A gl_lds][16 MFMA mt0-1] BAR_b
//             [1 A + 2 B gl_lds][24 MFMA mt2-4] vmcnt(7) BAR_c.

#define LDA(PB, MT, KS) (*(const bf16x8*)&As[(PB) + (KS)*AH_STR + a_off + (MT)*512])
#define LDB(PB, NT, KS) (*(const bf16x8*)&Bs[(PB) + (KS)*BH_STR + b_off + (NT)*512])

#define STG_A(KT, PDST, P) gl_lds16(asrc[P] + ((KT)<<6), &As[(PDST) + adst[P]])
#define STG_B(KT, PDST, Q) gl_lds16(bsrc[Q] + ((KT)<<6), &Bs[(PDST) + bdst[Q]])

#define GATE7 asm volatile("s_waitcnt vmcnt(7)" ::: "memory")
#define GATE0 asm volatile("s_waitcnt vmcnt(0)" ::: "memory")
#define NOOPS ((void)0)
#define AFENCE asm volatile("" ::: "memory")
#define BARR  { AFENCE; __builtin_amdgcn_s_barrier(); AFENCE; }

#define TILE_BODY(S1_STMT, S2_STMT, GATE_STMT) {                                  \
    bf16x8 af_[5][2], bf_[4][2];                                                  \
    _Pragma("unroll") for (int nt = 0; nt < 4; ++nt){                             \
        bf_[nt][0] = LDB(pB, nt, 0); bf_[nt][1] = LDB(pB, nt, 1); }               \
    _Pragma("unroll") for (int mt = 0; mt < 5; ++mt){                             \
        af_[mt][0] = LDA(pA, mt, 0); af_[mt][1] = LDA(pA, mt, 1); }               \
    S1_STMT;                                                                      \
    __builtin_amdgcn_s_setprio(1);                                                \
    _Pragma("unroll") for (int ks = 0; ks < 2; ++ks)                              \
      _Pragma("unroll") for (int nt = 0; nt < 4; ++nt)                            \
        _Pragma("unroll") for (int mt = 0; mt < 2; ++mt)                          \
          acc[mt][nt] = __builtin_amdgcn_mfma_f32_16x16x32_bf16(af_[mt][ks], bf_[nt][ks], acc[mt][nt], 0,0,0); \
    __builtin_amdgcn_s_setprio(0);                                                \
    BARR;                                                                         \
    S2_STMT;                                                                      \
    __builtin_amdgcn_s_setprio(1);                                                \
    _Pragma("unroll") for (int ks = 0; ks < 2; ++ks)                              \
      _Pragma("unroll") for (int nt = 0; nt < 4; ++nt)                            \
        _Pragma("unroll") for (int mt = 2; mt < 5; ++mt)                          \
          acc[mt][nt] = __builtin_amdgcn_mfma_f32_16x16x32_bf16(af_[mt][ks], bf_[nt][ks], acc[mt][nt], 0,0,0); \
    __builtin_amdgcn_s_setprio(0);                                                \
    GATE_STMT;                                                                    \
    BARR;                                                                         \
}

__global__ __launch_bounds__(512, 2) void gemm320(
    const unsigned short* __restrict__ Ag,
    const unsigned short* __restrict__ Bg,
    unsigned short* __restrict__ C,
    int M, int Cstride)
{
    __shared__ __align__(1024) unsigned short As[3*AB_STR]; // 120 KiB
    __shared__ __align__(1024) unsigned short Bs[2*BB_STR]; //  32 KiB

    // bijective XCD-chunked swizzle (nwg = 256, 256 % 8 == 0)
    const int bid = blockIdx.x;
    const int swz = (bid & 7)*32 + (bid >> 3);
    const int m0 = (swz >> 3) * BMT;   // 32 m-tiles
    const int n0 = (swz & 7) * BNT;    // 8 n-tiles

    const int tid = threadIdx.x;
    const int w   = tid >> 6,  l = tid & 63;
    const int wm  = w >> 1,    wn = w & 1;      // 4(M) x 2(N) wave grid: 80x64/wave
    const int l16 = l & 15,    quad = l >> 4;

    // staging: lane l writes LDS row (g*16 + l>>2), physical chunk (l&3);
    // global source chunk pre-swizzled by row-bit3 = l bit5.
    const int schunk = (l & 3) ^ (((l >> 5) & 1) << 1);
    // reads: logical chunk 'quad' -> physical chunk quad ^ ((row>>3)&1)<<1
    const int rq8   = ((quad ^ (((l16 >> 3) & 1) << 1)) << 3);
    const int a_off = ((wm*80 + l16) << 5) + rq8;
    const int b_off = ((wn*64 + l16) << 5) + rq8;

    // per-wave staging source pointers / LDS dest offsets (static-indexed)
    const unsigned short* asrc[5]; int adst[5];
    #pragma unroll
    for (int p = 0; p < 5; ++p){
        int j = 5*w + p, kh = j/20, g = j - kh*20;
        asrc[p] = Ag + (long)(m0 + g*16 + (l >> 2))*KP + (kh << 5) + (schunk << 3);
        adst[p] = kh*AH_STR + g*512;
    }
    const unsigned short* bsrc[2]; int bdst[2];
    #pragma unroll
    for (int q = 0; q < 2; ++q){
        int j = 2*w + q, kh = j >> 3, g = j & 7;
        bsrc[q] = Bg + (long)(n0 + g*16 + (l >> 2))*KP + (kh << 5) + (schunk << 3);
        bdst[q] = kh*BH_STR + g*512;
    }

    f32x4 acc[5][4];
    #pragma unroll
    for (int i = 0; i < 5; ++i)
        #pragma unroll
        for (int j = 0; j < 4; ++j)
            #pragma unroll
            for (int r = 0; r < 4; ++r) acc[i][j][r] = 0.f;

    // prologue: A(0),B(0)->buf0 [7], A(1),B(1)->buf1 [7]; drain tile-0's 7 only.
    #pragma unroll
    for (int p = 0; p < 5; ++p) STG_A(0, 0, p);
    #pragma unroll
    for (int q = 0; q < 2; ++q) STG_B(0, 0, q);
    #pragma unroll
    for (int p = 0; p < 5; ++p) STG_A(1, AB_STR, p);
    #pragma unroll
    for (int q = 0; q < 2; ++q) STG_B(1, BB_STR, q);
    GATE7;
    BARR;

    int ab = 0, bb = 0;   // buf of tile t: ab = t%3, bb = t&1
    #pragma unroll 1
    for (int t = 0; t < KTILES-2; ++t){
        const int pA  = ab*AB_STR;
        const int pB  = bb*BB_STR;                   // B(t) buf == B(t+2) dest buf
        const int ab2 = (ab == 0) ? 2 : ab - 1;      // (t+2)%3
        const int pA2 = ab2*AB_STR;
        TILE_BODY({ STG_A(t+2,pA2,0); STG_A(t+2,pA2,1); STG_A(t+2,pA2,2); STG_A(t+2,pA2,3); },
                  { STG_A(t+2,pA2,4); STG_B(t+2,pB,0); STG_B(t+2,pB,1); },
                  GATE7)
        ab = (ab == 2) ? 0 : ab + 1;
        bb ^= 1;
    }
    // peeled tile KTILES-2: no staging; full drain (tile-45's loads -> tile-47 data)
    {
        const int pA = ab*AB_STR, pB = bb*BB_STR;
        TILE_BODY(NOOPS, NOOPS, GATE0)
        ab = (ab == 2) ? 0 : ab + 1;
        bb ^= 1;
    }
    // peeled tile KTILES-1: no staging, no gate
    {
        const int pA = ab*AB_STR, pB = bb*BB_STR;
        TILE_BODY(NOOPS, NOOPS, NOOPS)
    }

    // epilogue: C/D layout col=lane&15, row=quad*4+reg
    #pragma unroll
    for (int mt = 0; mt < 5; ++mt){
        const int rowb = m0 + wm*80 + mt*16 + quad*4;
        #pragma unroll
        for (int nt = 0; nt < 4; ++nt){
            const int col = n0 + wn*64 + nt*16 + l16;
            #pragma unroll
            for (int r = 0; r < 4; ++r){
                const int row = rowb + r;
                if (row < M) C[(long)row*Cstride + col] = f2b(acc[mt][nt][r]);
            }
        }
    }
}

// ---------------- 64x64 MFMA GEMM: C = A[ridx?] @ BT^T (+epi) ----------------
// A: MxK bf16, BT: NnxK bf16, K % 64 == 0. epi: 0 none, 1 +bias, 2 +bias+prelu.
// obf: output bf16 (else f32). ridx: optional A row gather.
// K-unrolled x2: 64 k-cols staged per barrier round (halves barrier count).
// colsum != nullptr: additionally atomicAdd per-column sums of acc (NO bias) --
// used to fuse the DGI mean reduction into the posZ GEMM (bias folded in ws_k).
__device__ __forceinline__ void gemm_bt_body(
    const unsigned short* __restrict__ A,
    const unsigned short* __restrict__ BT,
    void* __restrict__ Cv,
    int M, int Nn, int K, int Cstride,
    const float* __restrict__ bias,
    const float* __restrict__ alpha,
    int epi, const int* __restrict__ ridx, int obf,
    float* __restrict__ colsum)
{
    __shared__ __align__(16) unsigned short As[2][64*40];
    __shared__ __align__(16) unsigned short Bs[2][64*40];
    const int m0 = blockIdx.y*64, n0 = blockIdx.x*64;
    const int t = threadIdx.x;
    const int lrow = t >> 2, lk = (t & 3) * 8;
    const int wave = t >> 6, lane = t & 63;
    const int quad = lane >> 4, l16 = lane & 15;
    f32x4 acc[4];
    #pragma unroll
    for (int i = 0; i < 4; i++)
        for (int j = 0; j < 4; j++) acc[i][j] = 0.f;

    const bool arv = (m0 + lrow) < M;
    const bool brv = (n0 + lrow) < Nn;
    long arow = 0;
    if (arv) arow = ridx ? (long)ridx[m0 + lrow] : (long)(m0 + lrow);
    const long arowbase = arow * K;
    const long browbase = (long)(n0 + lrow) * K;

    for (int k0 = 0; k0 < K; k0 += 64){
        uint4 av0 = {0u,0u,0u,0u}, av1 = {0u,0u,0u,0u};
        uint4 bv0 = {0u,0u,0u,0u}, bv1 = {0u,0u,0u,0u};
        if (arv){
            av0 = *(const uint4*)(A + arowbase + k0 + lk);
            av1 = *(const uint4*)(A + arowbase + k0 + 32 + lk);
        }
        if (brv){
            bv0 = *(const uint4*)(BT + browbase + k0 + lk);
            bv1 = *(const uint4*)(BT + browbase + k0 + 32 + lk);
        }
        *(uint4*)(&As[0][lrow*40 + lk]) = av0;
        *(uint4*)(&As[1][lrow*40 + lk]) = av1;
        *(uint4*)(&Bs[0][lrow*40 + lk]) = bv0;
        *(uint4*)(&Bs[1][lrow*40 + lk]) = bv1;
        __syncthreads();
        #pragma unroll
        for (int ks = 0; ks < 2; ++ks){
            bf16x8 af = *(const bf16x8*)(&As[ks][(wave*16 + l16)*40 + quad*8]);
            #pragma unroll
            for (int nt = 0; nt < 4; nt++){
                bf16x8 bfr = *(const bf16x8*)(&Bs[ks][(nt*16 + l16)*40 + quad*8]);
                acc[nt] = __builtin_amdgcn_mfma_f32_16x16x32_bf16(af, bfr, acc[nt], 0, 0, 0);
            }
        }
        __syncthreads();
    }

    const int rowb = m0 + wave*16 + quad*4;
    float aval = (epi == 2) ? alpha[0] : 0.f;
    #pragma unroll
    for (int nt = 0; nt < 4; nt++){
        int col = n0 + nt*16 + l16;
        if (col >= Nn) continue;
        float bvv = epi ? bias[col] : 0.f;
        #pragma unroll
        for (int r = 0; r < 4; r++){
            int row = rowb + r;
            if (row < M){
                float v = acc[nt][r] + bvv;
                if (epi == 2 && v < 0.f) v *= aval;
                if (obf) ((unsigned short*)Cv)[(long)row*Cstride + col] = f2b(v);
                else     ((float*)Cv)[(long)row*Cstride + col] = v;
            }
        }
    }

    if (colsum){
        // per-block column reduction of raw acc (invalid rows contribute 0).
        __syncthreads();
        float* cs = (float*)As;   // reuse LDS: 64 cols x 16 contributors
        #pragma unroll
        for (int nt = 0; nt < 4; nt++){
            float s = acc[nt][0] + acc[nt][1] + acc[nt][2] + acc[nt][3];
            cs[(nt*16 + l16)*16 + (wave*4 + quad)] = s;
        }
        __syncthreads();
        if (t < 64){
            float s = 0.f;
            #pragma unroll
            for (int j = 0; j < 16; ++j) s += cs[t*16 + j];
            atomicAdd(&colsum[n0 + t], s);
        }
    }
}

__global__ __launch_bounds__(256) void gemm_bt_ex(
    const unsigned short* __restrict__ A,
    const unsigned short* __restrict__ BT,
    void* __restrict__ Cv,
    int M, int Nn, int K, int Cstride,
    const float* __restrict__ bias,
    const float* __restrict__ alpha,
    int epi, const int* __restrict__ ridx, int obf)
{
    gemm_bt_body(A, BT, Cv, M, Nn, K, Cstride, bias, alpha, epi, ridx, obf, nullptr);
}

// z-batched pair variant: blockIdx.z selects the (A,B,C,bias,alpha) set.
// cs0: optional column-sum target for set 0 (posZ DGI mean fusion).
__global__ __launch_bounds__(256) void gemm_bt2(
    const unsigned short* __restrict__ A0, const unsigned short* __restrict__ A1,
    const unsigned short* __restrict__ B0, const unsigned short* __restrict__ B1,
    void* __restrict__ C0, void* __restrict__ C1,
    int M, int Nn, int K, int Cstride,
    const float* __restrict__ bias0, const float* __restrict__ bias1,
    const float* __restrict__ al0, const float* __restrict__ al1,
    int epi, const int* __restrict__ ridx, int obf,
    float* __restrict__ cs0)
{
    if (blockIdx.z == 0)
        gemm_bt_body(A0, B0, C0, M, Nn, K, Cstride, bias0, al0, epi, ridx, obf, cs0);
    else
        gemm_bt_body(A1, B1, C1, M, Nn, K, Cstride, bias1, al1, epi, ridx, obf, nullptr);
}

// 3-way fused launch: z=0/1 = projection-H (pos/neg, gathered rows, prelu),
// z=2 = decoder pre-matmul recPre (independent of both). Ragged grid with
// early-exit guards; launch (4, 157, 3).
__global__ __launch_bounds__(256) void gemm_bt3(
    const unsigned short* __restrict__ repP, const unsigned short* __restrict__ repN,
    const unsigned short* __restrict__ pW1T, const unsigned short* __restrict__ tpW1T,
    const unsigned short* __restrict__ e2dWT,
    unsigned short* __restrict__ posH, unsigned short* __restrict__ negH,
    unsigned short* __restrict__ recPre,
    const float* __restrict__ pb1, const float* __restrict__ tpb1,
    const float* __restrict__ pa, const float* __restrict__ tpa,
    const int* __restrict__ perm)
{
    int z = blockIdx.z;
    if (z == 0){
        if (blockIdx.y < 47)
            gemm_bt_body(repP, pW1T, posH, NM, PP, LL, PP, pb1, pa, 2, perm, 1, nullptr);
    } else if (z == 1){
        if (blockIdx.y < 47)
            gemm_bt_body(repN, tpW1T, negH, NM, PP, LL, PP, tpb1, tpa, 2, perm, 1, nullptr);
    } else {
        if (blockIdx.x < 2)
            gemm_bt_body(repP, e2dWT, recPre, NND, LL, LL, LL, nullptr, nullptr, 0, nullptr, 1, nullptr);
    }
}

// ---------------- fused GCN layer-1 aggregation (pos + neg), bf16 I/O ----------------
// warps 0-1: pos half (XW cols [0,512)); warps 2-3: neg half (cols [512,1024) of
// gathered negsrc rows). uint2 loads (4 cols/thread). flag branches are
// block-uniform -> masked neg gathers are SKIPPED entirely (~30% of edges).

__global__ __launch_bounds__(256) void agg1_k(const unsigned short* __restrict__ XW,
    const float* __restrict__ ptW, const float* __restrict__ ntW,
    const int* __restrict__ flag, const int* __restrict__ negsrc,
    const float* __restrict__ dinv, const int* __restrict__ rowptr,
    const int* __restrict__ degi, const int* __restrict__ adj,
    const float* __restrict__ sb1, const float* __restrict__ sav,
    const float* __restrict__ tb1, const float* __restrict__ tav,
    unsigned short* __restrict__ H1p, unsigned short* __restrict__ H1n)
{
    int i = blockIdx.x; int t = threadIdx.x;
    int half = t >> 7;          // 0 = pos, 1 = neg
    int c = (t & 127) * 4;      // cols c..c+3 in [0,512)
    float di = dinv[i];
    int rs = rowptr[i], re = rs + degi[i];
    int fi = flag[i];
    float a0, a1, a2, a3;

    if (half == 0){
        float p0 = ptW[c], p1 = ptW[c+1], p2 = ptW[c+2], p3 = ptW[c+3];
        uint2 v = *(const uint2*)(XW + (long)i*1024 + c);
        float2 va = bpair(v.x), vb = bpair(v.y);
        float ffi = fi ? 1.f : 0.f;
        a0 = (va.x + ffi*p0)*di; a1 = (va.y + ffi*p1)*di;
        a2 = (vb.x + ffi*p2)*di; a3 = (vb.y + ffi*p3)*di;
        for (int e = rs; e < re; ++e){
            int s = adj[e]; float ds = dinv[s];
            float ffs = flag[s] ? 1.f : 0.f;
            uint2 w = *(const uint2*)(XW + (long)s*1024 + c);
            float2 wa = bpair(w.x), wb = bpair(w.y);
            a0 += (wa.x + ffs*p0)*ds; a1 += (wa.y + ffs*p1)*ds;
            a2 += (wb.x + ffs*p2)*ds; a3 += (wb.y + ffs*p3)*ds;
        }
        float sa_ = sav[0];
        float v0 = di*a0 + sb1[c];   if (v0 < 0.f) v0 *= sa_;
        float v1 = di*a1 + sb1[c+1]; if (v1 < 0.f) v1 *= sa_;
        float v2 = di*a2 + sb1[c+2]; if (v2 < 0.f) v2 *= sa_;
        float v3 = di*a3 + sb1[c+3]; if (v3 < 0.f) v3 *= sa_;
        uint2 o; o.x = packb(v0, v1); o.y = packb(v2, v3);
        *(uint2*)(H1p + (long)i*512 + c) = o;
    } else {
        float n0 = ntW[c], n1 = ntW[c+1], n2 = ntW[c+2], n3 = ntW[c+3];
        if (fi){ a0 = n0*di; a1 = n1*di; a2 = n2*di; a3 = n3*di; }
        else {
            int nsi = negsrc[i];
            uint2 v = *(const uint2*)(XW + (long)nsi*1024 + 512 + c);
            float2 va = bpair(v.x), vb = bpair(v.y);
            a0 = va.x*di; a1 = va.y*di; a2 = vb.x*di; a3 = vb.y*di;
        }
        for (int e = rs; e < re; ++e){
            int s = adj[e]; float ds = dinv[s];
            if (flag[s]){ a0 += n0*ds; a1 += n1*ds; a2 += n2*ds; a3 += n3*ds; }
            else {
                int ns = negsrc[s];
                uint2 w = *(const uint2*)(XW + (long)ns*1024 + 512 + c);
                float2 wa = bpair(w.x), wb = bpair(w.y);
                a0 += wa.x*ds; a1 += wa.y*ds; a2 += wb.x*ds; a3 += wb.y*ds;
            }
        }
        float ta_ = tav[0];
        float v0 = di*a0 + tb1[c];   if (v0 < 0.f) v0 *= ta_;
        float v1 = di*a1 + tb1[c+1]; if (v1 < 0.f) v1 *= ta_;
        float v2 = di*a2 + tb1[c+2]; if (v2 < 0.f) v2 *= ta_;
        float v3 = di*a3 + tb1[c+3]; if (v3 < 0.f) v3 *= ta_;
        uint2 o; o.x = packb(v0, v1); o.y = packb(v2, v3);
        *(uint2*)(H1n + (long)i*512 + c) = o;
    }
}

// fused pos/neg second-layer aggregation: wave 0 = pos, wave 1 = neg (one block
// per node -> adj/dinv scalar loads shared via L1); uint loads (2 cols/thread).
__global__ __launch_bounds__(128) void agg128_k(
    const unsigned short* __restrict__ In0, const unsigned short* __restrict__ In1,
    const float* __restrict__ dinv, const int* __restrict__ rowptr,
    const int* __restrict__ degi, const int* __restrict__ adj,
    const float* __restrict__ b20, const float* __restrict__ b21,
    const float* __restrict__ a20, const float* __restrict__ a21,
    unsigned short* __restrict__ Out0, unsigned short* __restrict__ Out1)
{
    int i = blockIdx.x, t = threadIdx.x;
    int h = t >> 6;
    int c = (t & 63) * 2;
    const unsigned short* In = h ? In1 : In0;
    const float* b2 = h ? b21 : b20;
    const float* a2 = h ? a21 : a20;
    unsigned short* Out = h ? Out1 : Out0;
    float di = dinv[i];
    int rs = rowptr[i], re = rs + degi[i];
    float2 sv = bpair(*(const unsigned int*)(In + (long)i*128 + c));
    float acc0 = sv.x * di, acc1 = sv.y * di;
    for (int e = rs; e < re; ++e){
        int s = adj[e]; float ds = dinv[s];
        float2 w = bpair(*(const unsigned int*)(In + (long)s*128 + c));
        acc0 += w.x * ds; acc1 += w.y * ds;
    }
    float a = a2[0];
    float v0 = di*acc0 + b2[c];   if (v0 < 0.f) v0 *= a;
    float v1 = di*acc1 + b2[c+1]; if (v1 < 0.f) v1 *= a;
    *(unsigned int*)(Out + (long)i*128 + c) = packb(v0, v1);
}

// decoder aggregation over unmasked neighbors; uint loads, masked gathers skipped.
__global__ __launch_bounds__(64) void aggrec_k(const unsigned short* __restrict__ recPre,
    const float* __restrict__ dinv, const int* __restrict__ rowptr,
    const int* __restrict__ degi, const int* __restrict__ adj,
    const int* __restrict__ flag, const int* __restrict__ perm,
    unsigned short* __restrict__ recAgg)
{
    int b = blockIdx.x, t = threadIdx.x;
    int c = t * 2;
    int i = perm[b];
    float di = dinv[i];
    int rs = rowptr[i], re = rs + degi[i];
    float acc0 = 0.f, acc1 = 0.f; // self loop: i is a mask node -> rec row zeroed
    for (int e = rs; e < re; ++e){
        int s = adj[e];
        if (!flag[s]){
            float ds = dinv[s];
            float2 w = bpair(*(const unsigned int*)(recPre + (long)s*128 + c));
            acc0 += w.x * ds; acc1 += w.y * ds;
        }
    }
    *(unsigned int*)(recAgg + (long)b*128 + c) = packb(di*acc0, di*acc1);
}

// ---------------- DGI head ----------------
// (meanp fused into the posZ GEMM colsum epilogue; svecraw = colsum of raw acc,
//  bias folded analytically here: mean = svecraw/NM + pb2.)

__global__ void ws_k(const float* __restrict__ dgiW, const float* __restrict__ svecraw,
                     const float* __restrict__ pb2, float* wsv){
    __shared__ float s[128];
    int i = threadIdx.x; // 128
    s[i] = 1.f/(1.f + expf(-(svecraw[i]/(float)NM + pb2[i])));
    __syncthreads();
    float a = 0.f;
    for (int j = 0; j < 128; ++j) a += dgiW[i*128 + j] * s[j];
    wsv[i] = a;
}

// grid-stride rows; per-wave accumulate; 2 atomics per block.
__global__ __launch_bounds__(256) void dgi_k(const float* __restrict__ posZ,
    const float* __restrict__ negZ, const float* __restrict__ wsv, float* scal){
    __shared__ float sp[4], sn[4];
    int wid = threadIdx.x >> 6, lane = threadIdx.x & 63;
    float w0 = wsv[lane], w1 = wsv[64 + lane];
    float accp = 0.f, accn = 0.f;
    for (int row = blockIdx.x*4 + wid; row < 2*NM; row += gridDim.x*4){
        const float* Z = (row < NM) ? posZ : negZ;
        int r = (row < NM) ? row : row - NM;
        float v = Z[(long)r*128 + lane] * w0 + Z[(long)r*128 + 64 + lane] * w1;
        for (int off = 32; off; off >>= 1) v += __shfl_down(v, off, 64);
        if (lane == 0){
            float d = 1.f/(1.f + expf(-v));
            if (row < NM) accp += logf(d + 1e-15f);
            else          accn += logf(1.f - d + 1e-15f);
        }
    }
    if (lane == 0){ sp[wid] = accp; sn[wid] = accn; }
    __syncthreads();
    if (threadIdx.x == 0){
        atomicAdd(&scal[0], sp[0]+sp[1]+sp[2]+sp[3]);
        atomicAdd(&scal[1], sn[0]+sn[1]+sn[2]+sn[3]);
    }
}

// ---------------- cosine feature loss ----------------
// 8 cols/thread: float4 x reads, uint4 recMask reads.

__global__ __launch_bounds__(256) void cos_k(const float* __restrict__ x,
    const unsigned short* __restrict__ recMask, const int* __restrict__ perm,
    float* scal){
    int b = blockIdx.x, t = threadIdx.x;
    long xi = (long)perm[b]*DD;
    long ri = (long)b*DD;
    float dot = 0.f, nx = 0.f, nr = 0.f;
    for (int d0 = t*8; d0 < DD; d0 += 2048){
        float4 xa = *(const float4*)(x + xi + d0);
        float4 xb2 = *(const float4*)(x + xi + d0 + 4);
        uint4 rv = *(const uint4*)(recMask + ri + d0);
        float2 r0 = bpair(rv.x), r1 = bpair(rv.y), r2 = bpair(rv.z), r3 = bpair(rv.w);
        dot += xa.x*r0.x + xa.y*r0.y + xa.z*r1.x + xa.w*r1.y
             + xb2.x*r2.x + xb2.y*r2.y + xb2.z*r3.x + xb2.w*r3.y;
        nx  += xa.x*xa.x + xa.y*xa.y + xa.z*xa.z + xa.w*xa.w
             + xb2.x*xb2.x + xb2.y*xb2.y + xb2.z*xb2.z + xb2.w*xb2.w;
        nr  += r0.x*r0.x + r0.y*r0.y + r1.x*r1.x + r1.y*r1.y
             + r2.x*r2.x + r2.y*r2.y + r3.x*r3.x + r3.y*r3.y;
    }
    for (int off = 32; off; off >>= 1){
        dot += __shfl_down(dot, off, 64);
        nx  += __shfl_down(nx,  off, 64);
        nr  += __shfl_down(nr,  off, 64);
    }
    __shared__ float sd[4], sx[4], sr[4];
    int w = t >> 6, lane = t & 63;
    if (lane == 0){ sd[w] = dot; sx[w] = nx; sr[w] = nr; }
    __syncthreads();
    if (t == 0){
        float Dv = sd[0]+sd[1]+sd[2]+sd[3];
        float Xv = sx[0]+sx[1]+sx[2]+sx[3];
        float Rv = sr[0]+sr[1]+sr[2]+sr[3];
        float c = Dv/(fmaxf(sqrtf(Xv),1e-12f)*fmaxf(sqrtf(Rv),1e-12f));
        float e = 1.f - c;
        atomicAdd(&scal[16 + (b & 63)], e*e);   // 64-way spread -> ~47 per slot
    }
}

__global__ void fin_k(const float* __restrict__ scal, float* out){
    float fs = 0.f;
    for (int i = 0; i < 64; ++i) fs += scal[16 + i];
    float feat = fs/(float)NM;
    float dgi  = -(scal[0]/(float)NM) - (scal[1]/(float)NM);
    out[0] = feat;
    out[1] = dgi;
}

// ---------------- launch ----------------

extern "C" void kernel_launch(void* const* d_in, const int* in_sizes, int n_in,
                              void* d_out, int out_size, void* d_ws, size_t ws_size,
                              hipStream_t stream) {
    (void)in_sizes; (void)n_in; (void)out_size; (void)d_ws; (void)ws_size;
    const float* x  = (const float*)d_in[0];
    const int* ei   = (const int*)d_in[1];
    const int* perm = (const int*)d_in[2];
    const int* shuf = (const int*)d_in[3];
    const float* sW1 = (const float*)d_in[4];
    const float* sb1 = (const float*)d_in[5];
    const float* sa  = (const float*)d_in[6];
    const float* sW2 = (const float*)d_in[7];
    const float* sb2 = (const float*)d_in[8];
    const float* tW1 = (const float*)d_in[9];
    const float* tb1 = (const float*)d_in[10];
    const float* ta  = (const float*)d_in[11];
    const float* tW2 = (const float*)d_in[12];
    const float* tb2 = (const float*)d_in[13];
    const float* pW1 = (const float*)d_in[14];
    const float* pb1 = (const float*)d_in[15];
    const float* pa  = (const float*)d_in[16];
    const float* pW2 = (const float*)d_in[17];
    const float* pb2 = (const float*)d_in[18];
    const float* tpW1 = (const float*)d_in[19];
    const float* tpb1 = (const float*)d_in[20];
    const float* tpa  = (const float*)d_in[21];
    const float* tpW2 = (const float*)d_in[22];
    const float* tpb2 = (const float*)d_in[23];
    const float* dgiW = (const float*)d_in[24];
    const float* posT = (const float*)d_in[25];
    const float* negT = (const float*)d_in[26];
    const float* e2dW = (const float*)d_in[27];
    const float* dW   = (const float*)d_in[28];
    const float* db   = (const float*)d_in[29];
    float* out = (float*)d_out;

    void* wsp = nullptr;
    hipGetSymbolAddress(&wsp, HIP_SYMBOL(g_ws));
    char* base = (char*)wsp;
    size_t off = 0;
    auto alloc = [&](size_t b){ size_t o = off; off = (off + b + 255) & ~(size_t)255; return o; };

    float* dinv    = (float*)(base + alloc(NND*4));
    int* degi      = (int*)  (base + alloc(NND*4));
    int* rowptr    = (int*)  (base + alloc(NND*4));
    int* cursor    = (int*)  (base + alloc(NND*4));
    int* adj       = (int*)  (base + alloc(EE*4));
    int* flag      = (int*)  (base + alloc(NND*4));
    int* negsrc    = (int*)  (base + alloc(NND*4));
    int* ecnt      = (int*)  (base + alloc(16*4));
    float* ptW     = (float*)(base + alloc(HH*4));
    float* ntW     = (float*)(base + alloc(HH*4));
    float* svecraw = (float*)(base + alloc(128*4));
    float* wsv     = (float*)(base + alloc(128*4));
    float* scal    = (float*)(base + alloc(80*4));

    unsigned short* xb    = (unsigned short*)(base + alloc((size_t)MP*KP*2));
    unsigned short* W1T   = (unsigned short*)(base + alloc((size_t)NW*KP*2));
    unsigned short* sW2T  = (unsigned short*)(base + alloc((size_t)LL*HH*2));
    unsigned short* tW2T  = (unsigned short*)(base + alloc((size_t)LL*HH*2));
    unsigned short* pW1T  = (unsigned short*)(base + alloc((size_t)PP*LL*2));
    unsigned short* pW2T  = (unsigned short*)(base + alloc((size_t)LL*PP*2));
    unsigned short* tpW1T = (unsigned short*)(base + alloc((size_t)PP*LL*2));
    unsigned short* tpW2T = (unsigned short*)(base + alloc((size_t)LL*PP*2));
    unsigned short* e2dWT = (unsigned short*)(base + alloc((size_t)LL*LL*2));
    unsigned short* dWT   = (unsigned short*)(base + alloc((size_t)DD*LL*2));

    unsigned short* XW      = (unsigned short*)(base + alloc((size_t)NND*1024*2));
    unsigned short* H1p     = (unsigned short*)(base + alloc((size_t)NND*512*2));
    unsigned short* H1n     = (unsigned short*)(base + alloc((size_t)NND*512*2));
    unsigned short* M2p     = (unsigned short*)(base + alloc((size_t)NND*128*2));
    unsigned short* M2n     = (unsigned short*)(base + alloc((size_t)NND*128*2));
    unsigned short* repP    = (unsigned short*)(base + alloc((size_t)NND*128*2));
    unsigned short* repN    = (unsigned short*)(base + alloc((size_t)NND*128*2));
    unsigned short* posH    = (unsigned short*)(base + alloc((size_t)NM*256*2));
    unsigned short* negH    = (unsigned short*)(base + alloc((size_t)NM*256*2));
    float* posZ             = (float*)(base + alloc((size_t)NM*128*4));
    float* negZ             = (float*)(base + alloc((size_t)NM*128*4));
    unsigned short* recPre  = (unsigned short*)(base + alloc((size_t)NND*128*2));
    unsigned short* recAgg  = (unsigned short*)(base + alloc((size_t)NM*128*2));
    unsigned short* recMask = (unsigned short*)(base + alloc((size_t)NM*DD*2));

    // ---- graph build (scan-free) ----
    init_k<<<(NND+255)/256, 256, 0, stream>>>(degi, cursor, scal, ptW, ntW, svecraw, ecnt);
    build_k<<<(EE+255)/256, 256, 0, stream>>>(ei, perm, shuf, degi, flag, negsrc);
    alloc_k<<<(NND+255)/256, 256, 0, stream>>>(degi, dinv, rowptr, ecnt);
    fill_k<<<(EE+255)/256, 256, 0, stream>>>(ei, rowptr, cursor, adj);

    // ---- bf16 staging + token sums (single mega dispatch) ----
    {
        TBatch tb;
        const float* ins[10] = {sW1, tW1, sW2, tW2, pW1, pW2, tpW1, tpW2, e2dW, dW};
        unsigned short* outs[10] = {W1T, W1T + (size_t)HH*KP, sW2T, tW2T, pW1T, pW2T,
                                    tpW1T, tpW2T, e2dWT, dWT};
        int Rs[10]  = {DD, DD, HH, HH, LL, PP, LL, PP, LL, LL};
        int Cs[10]  = {HH, HH, LL, LL, PP, LL, PP, LL, LL, DD};
        int OSs[10] = {KP, KP, HH, HH, LL, PP, LL, PP, LL, LL};
        int cum = 0;
        for (int d = 0; d < 10; d++){
            tb.in[d] = ins[d]; tb.out[d] = outs[d];
            tb.R[d] = Rs[d]; tb.C[d] = Cs[d]; tb.OS[d] = OSs[d];
            tb.t0[d] = cum;
            cum += (OSs[d]/32) * ((Cs[d] + 31)/32);
        }
        tb.t0[10] = cum;
        stage_k<<<CASTB + cum + 256, 256, 0, stream>>>(tb, x, xb, posT, negT,
                                                       sW1, tW1, ptW, ntW);
    }

    // ---- encoder layer 1 (MFMA 320x128, 256 blocks) + fused aggregation ----
    gemm320<<<256, 512, 0, stream>>>(xb, W1T, XW, NND, 1024);
    agg1_k<<<NND, 256, 0, stream>>>(XW, ptW, ntW, flag, negsrc, dinv, rowptr, degi, adj,
                                    sb1, sa, tb1, ta, H1p, H1n);

    // ---- encoder layer 2 (MFMA, z-batched pair) + fused aggregation ----
    gemm_bt2<<<dim3(2,157,2), 256, 0, stream>>>(H1p, H1n, sW2T, tW2T, M2p, M2n,
                                                NND, LL, HH, LL,
                                                nullptr, nullptr, nullptr, nullptr,
                                                0, nullptr, 1, nullptr);
    agg128_k<<<NND, 128, 0, stream>>>(M2p, M2n, dinv, rowptr, degi, adj,
                                      sb2, tb2, sa, ta, repP, repN);

    // ---- projections-H (pos+neg) + decoder recPre, one ragged z=3 launch ----
    gemm_bt3<<<dim3(4,157,3), 256, 0, stream>>>(repP, repN, pW1T, tpW1T, e2dWT,
                                                posH, negH, recPre,
                                                pb1, tpb1, pa, tpa, perm);
    // posZ/negZ; posZ side also accumulates DGI column sums (meanp fused).
    gemm_bt2<<<dim3(2,47,2), 256, 0, stream>>>(posH, negH, pW2T, tpW2T, posZ, negZ,
                                               NM, LL, PP, LL,
                                               pb2, tpb2, nullptr, nullptr, 1, nullptr, 0,
                                               svecraw);

    // ---- decoder aggregation + reconstruction ----
    aggrec_k<<<NM, 64, 0, stream>>>(recPre, dinv, rowptr, degi, adj, flag, perm, recAgg);
    gemm_bt_ex<<<dim3(47,47), 256, 0, stream>>>(recAgg, dWT, recMask, NM, DD, LL, DD,
                                                db, nullptr, 1, nullptr, 1);

    // ---- DGI loss ----
    ws_k<<<1, 128, 0, stream>>>(dgiW, svecraw, pb2, wsv);
    dgi_k<<<128, 256, 0, stream>>>(posZ, negZ, wsv, scal);

    // ---- feature loss ----
    cos_k<<<NM, 256, 0, stream>>>(x, recMask, perm, scal);

    fin_k<<<1, 1, 0, stream>>>(scal, out);
}

// Round 9
// 456.127 us; speedup vs baseline: 1.1417x; 1.0027x over previous
//
#include <hip/hip_runtime.h>

#define NND 10000
#define EE  60000
#define DD  3000
#define HH  512
#define LL  128
#define PP  256
#define NM  3000

// padded dims for the big MFMA GEMM (no tail guards in hot loop)
#define KP  3072            // 48 * 64
#define MP  10240           // 32 * 320
#define NW  1024            // [sW1|tW1] fused width, 8*128
#define KTILES (KP/64)      // 48

// gemm320 tile geometry
#define BMT 320
#define BNT 128
#define AH_STR 10240        // elems per A k-half (320 rows x 32)
#define AB_STR 20480        // elems per A buf (2 k-halves)
#define BH_STR 4096         // elems per B k-half (128 rows x 32)
#define BB_STR 8192         // elems per B buf

typedef short bf16x8 __attribute__((ext_vector_type(8)));
typedef float f32x4 __attribute__((ext_vector_type(4)));

// All scratch lives in module BSS -> no dependency on harness ws_size.
__device__ __align__(256) char g_ws[(size_t)176 << 20];

__device__ __forceinline__ unsigned short f2b(float f){
    unsigned int x = __float_as_uint(f);
    unsigned int r = x + 0x7FFFu + ((x >> 16) & 1u);
    return (unsigned short)(r >> 16);
}
__device__ __forceinline__ float b2f(unsigned short u){
    return __uint_as_float(((unsigned int)u) << 16);
}
// uint holding 2 bf16 (low = col c, high = col c+1)
__device__ __forceinline__ float2 bpair(unsigned int u){
    float2 r;
    r.x = __uint_as_float(u << 16);
    r.y = __uint_as_float(u & 0xffff0000u);
    return r;
}
__device__ __forceinline__ unsigned int packb(float a, float b){
    return (unsigned int)f2b(a) | ((unsigned int)f2b(b) << 16);
}

__device__ __forceinline__ void gl_lds16(const void* g, void* l){
    __builtin_amdgcn_global_load_lds(
        (const __attribute__((address_space(1))) unsigned int*)g,
        (__attribute__((address_space(3))) unsigned int*)l, 16, 0, 0);
}

// ---------------- init / graph build ----------------

__global__ void init_k(int* degi, int* cursor, float* scal,
                       float* ptW, float* ntW, float* svecraw, int* ecnt){
    int i = blockIdx.x*256 + threadIdx.x;
    if (i < NND){ degi[i]=0; cursor[i]=0; }
    if (i < 80) scal[i]=0.f;           // [0]=dgi-pos [1]=dgi-neg [16..79]=cos slots
    if (i == 0) ecnt[0]=0;
    if (i < 128) svecraw[i]=0.f;
    if (i < HH){ ptW[i]=0.f; ntW[i]=0.f; }
}

// merged: degree count (i < EE) + mask flags (i < NND)
__global__ void build_k(const int* __restrict__ ei,
                        const int* __restrict__ perm, const int* __restrict__ shuf,
                        int* degi, int* flag, int* negsrc){
    int i = blockIdx.x*256 + threadIdx.x;
    if (i < EE) atomicAdd(&degi[ei[EE + i]], 1);
    if (i < NND){
        int p = perm[i];
        if (i < NM){ flag[p] = 1; negsrc[p] = -1; }
        else       { flag[p] = 0; negsrc[p] = perm[NM + shuf[i - NM]]; }
    }
}

// dinv + CSR segment allocation (order-free; per-block scan, 1 atomic/block)
__global__ __launch_bounds__(256) void alloc_k(const int* __restrict__ degi,
                                               float* dinv, int* rowptr, int* ecnt){
    __shared__ int sb[256];
    __shared__ int bbase;
    int t = threadIdx.x;
    int i = blockIdx.x*256 + t;
    int v = (i < NND) ? degi[i] : 0;
    sb[t] = v;
    __syncthreads();
    for (int off = 1; off < 256; off <<= 1){
        int x = 0;
        if (t >= off) x = sb[t - off];
        __syncthreads();
        sb[t] += x;
        __syncthreads();
    }
    if (t == 255) bbase = atomicAdd(ecnt, sb[255]);
    __syncthreads();
    if (i < NND){
        rowptr[i] = bbase + sb[t] - v;
        dinv[i] = 1.f/sqrtf((float)(degi[i] + 1));
    }
}

__global__ void fill_k(const int* __restrict__ ei, const int* __restrict__ rowptr,
                       int* cursor, int* adj){
    int i = blockIdx.x*256 + threadIdx.x;
    if (i < EE){
        int d = ei[EE + i];
        int s = ei[i];
        int p = atomicAdd(&cursor[d], 1);
        adj[rowptr[d] + p] = s;
    }
}

// ---------------- mega staging: cast_pad + transbatch + tok in ONE dispatch ----
// Cast region is GRID-STRIDED over 4096 blocks (~4 chunks/thread) so each
// thread has several independent load->cvt->store chains in flight (ILP) —
// round-8's one-chunk-per-thread version ran at 2 TB/s (25% HBM), VALU 11%.
// 384 chunks/row = exactly 6 waves -> every wave's reads/writes stay within
// one row, fully coalesced. trans/tok blocks now launch concurrently.

struct TBatch {
    const float* in[10];
    unsigned short* out[10];
    int R[10], C[10], OS[10];
    int t0[11];
};

#define CAST_BLOCKS 4096

__global__ __launch_bounds__(256) void stage_k(TBatch tb,
    const float* __restrict__ x, unsigned short* __restrict__ xb,
    const float* __restrict__ posT, const float* __restrict__ negT,
    const float* __restrict__ sW1, const float* __restrict__ tW1,
    float* ptW, float* ntW)
{
    __shared__ unsigned short tile[32][33];
    int b = blockIdx.x;
    int t = threadIdx.x;
    if (b < CAST_BLOCKS){
        const long total = (long)MP*(KP/8);
        for (long idx = (long)b*256 + t; idx < total; idx += (long)CAST_BLOCKS*256){
            int row = (int)(idx / (KP/8));
            int g   = (int)(idx % (KP/8));
            unsigned short o[8] = {0,0,0,0,0,0,0,0};
            if (row < NND && g < DD/8){
                const float* src = x + (long)row*DD + g*8;
                float4 a = *(const float4*)(src);
                float4 bb = *(const float4*)(src + 4);
                o[0]=f2b(a.x); o[1]=f2b(a.y); o[2]=f2b(a.z); o[3]=f2b(a.w);
                o[4]=f2b(bb.x); o[5]=f2b(bb.y); o[6]=f2b(bb.z); o[7]=f2b(bb.w);
            }
            *(uint4*)(xb + (long)row*KP + g*8) = *(const uint4*)o;
        }
        return;
    }
    b -= CAST_BLOCKS;
    if (b < tb.t0[10]){
        // transpose-cast: out[c*OS + r] = bf16(in[r*C + c]), zero-fill r in [R,OS)
        int d = 0;
        while (d < 9 && b >= tb.t0[d+1]) d++;
        const float* in = tb.in[d];
        unsigned short* out = tb.out[d];
        int R = tb.R[d], C = tb.C[d], OS = tb.OS[d];
        int lt = b - tb.t0[d];
        int Ctiles = (C + 31) >> 5;
        int rt = lt / Ctiles, ct = lt % Ctiles;
        int rb = rt*32, cb = ct*32;
        int tx = t & 31, ty = t >> 5;   // (32,8)
        for (int i = ty; i < 32; i += 8){
            int r = rb + i, c = cb + tx;
            tile[i][tx] = (r < R && c < C) ? f2b(in[(long)r*C + c]) : (unsigned short)0;
        }
        __syncthreads();
        for (int i = ty; i < 32; i += 8){
            int c = cb + i, r = rb + tx;
            if (c < C && r < OS) out[(long)c*OS + r] = (r < R) ? tile[tx][i] : (unsigned short)0;
        }
        return;
    }
    b -= tb.t0[10];
    // token @ W1 partial sums: 256 sub-blocks (b&1 = pos/neg, b>>1 = row chunk)
    int tokb = b & 1, chunk = b >> 1;
    const float* tok = tokb ? negT : posT;
    const float* Wm  = tokb ? tW1 : sW1;
    float acc0 = 0.f, acc1 = 0.f;
    int d0 = chunk*24, d1 = d0 + 24; if (d1 > DD) d1 = DD;
    for (int d = d0; d < d1; ++d){
        float tv = tok[d];
        acc0 += tv * Wm[(long)d*HH + t];
        acc1 += tv * Wm[(long)d*HH + t + 256];
    }
    float* dst = tokb ? ntW : ptW;
    atomicAdd(&dst[t], acc0);
    atomicAdd(&dst[t+256], acc1);
}

// ---------------- 320x128 MFMA GEMM, 256 blocks (1/CU), 2-barrier tiles --------
// (round-5 structure, 74.4us / VGPR 92 — do not touch; round-6's pipeline
//  attempt spilled. See journal.)
// A: MP x KP bf16, Bg: NW x KP bf16 (row = output col). C guarded to M rows.
// A triple-buffered (3 x 40 KiB), B double-buffered (2 x 16 KiB) = 152 KiB LDS.
// Per K-tile: [18 frag ds_reads + 4 A gl_lds][16 MFMA mt0-1] BAR_b
//             [1 A + 2 B gl_lds][24 MFMA mt2-4] vmcnt(7) BAR_c.

#define LDA(PB, MT, KS) (*(const bf16x8*)&As[(PB) + (KS)*AH_STR + a_off + (MT)*512])
#define LDB(PB, NT, KS) (*(const bf16x8*)&Bs[(PB) + (KS)*BH_STR + b_off + (NT)*512])

#define STG_A(KT, PDST, P) gl_lds16(asrc[P] + ((KT)<<6), &As[(PDST) + adst[P]])
#define STG_B(KT, PDST, Q) gl_lds16(bsrc[Q] + ((KT)<<6), &Bs[(PDST) + bdst[Q]])

#define GATE7 asm volatile("s_waitcnt vmcnt(7)" ::: "memory")
#define GATE0 asm volatile("s_waitcnt vmcnt(0)" ::: "memory")
#define NOOPS ((void)0)
#define AFENCE asm volatile("" ::: "memory")
#define BARR  { AFENCE; __builtin_amdgcn_s_barrier(); AFENCE; }

#define TILE_BODY(S1_STMT, S2_STMT, GATE_STMT) {                                  \
    bf16x8 af_[5][2], bf_[4][2];                                                  \
    _Pragma("unroll") for (int nt = 0; nt < 4; ++nt){                             \
        bf_[nt][0] = LDB(pB, nt, 0); bf_[nt][1] = LDB(pB, nt, 1); }               \
    _Pragma("unroll") for (int mt = 0; mt < 5; ++mt){                             \
        af_[mt][0] = LDA(pA, mt, 0); af_[mt][1] = LDA(pA, mt, 1); }               \
    S1_STMT;                                                                      \
    __builtin_amdgcn_s_setprio(1);                                                \
    _Pragma("unroll") for (int ks = 0; ks < 2; ++ks)                              \
      _Pragma("unroll") for (int nt = 0; nt < 4; ++nt)                            \
        _Pragma("unroll") for (int mt = 0; mt < 2; ++mt)                          \
          acc[mt][nt] = __builtin_amdgcn_mfma_f32_16x16x32_bf16(af_[mt][ks], bf_[nt][ks], acc[mt][nt], 0,0,0); \
    __builtin_amdgcn_s_setprio(0);                                                \
    BARR;                                                                         \
    S2_STMT;                                                                      \
    __builtin_amdgcn_s_setprio(1);                                                \
    _Pragma("unroll") for (int ks = 0; ks < 2; ++ks)                              \
      _Pragma("unroll") for (int nt = 0; nt < 4; ++nt)                            \
        _Pragma("unroll") for (int mt = 2; mt < 5; ++mt)                          \
          acc[mt][nt] = __builtin_amdgcn_mfma_f32_16x16x32_bf16(af_[mt][ks], bf_[nt][ks], acc[mt][nt], 0,0,0); \
    __builtin_amdgcn_s_setprio(0);                                                \
    GATE_STMT;                                                                    \
    BARR;                                                                         \
}

__global__ __launch_bounds__(512, 2) void gemm320(
    const unsigned short* __restrict__ Ag,
    const unsigned short* __restrict__ Bg,
    unsigned short* __restrict__ C,
    int M, int Cstride)
{
    __shared__ __align__(1024) unsigned short As[3*AB_STR]; // 120 KiB
    __shared__ __align__(1024) unsigned short Bs[2*BB_STR]; //  32 KiB

    // bijective XCD-chunked swizzle (nwg = 256, 256 % 8 == 0)
    const int bid = blockIdx.x;
    const int swz = (bid & 7)*32 + (bid >> 3);
    const int m0 = (swz >> 3) * BMT;   // 32 m-tiles
    const int n0 = (swz & 7) * BNT;    // 8 n-tiles

    const int tid = threadIdx.x;
    const int w   = tid >> 6,  l = tid & 63;
    const int wm  = w >> 1,    wn = w & 1;      // 4(M) x 2(N) wave grid: 80x64/wave
    const int l16 = l & 15,    quad = l >> 4;

    // staging: lane l writes LDS row (g*16 + l>>2), physical chunk (l&3);
    // global source chunk pre-swizzled by row-bit3 = l bit5.
    const int schunk = (l & 3) ^ (((l >> 5) & 1) << 1);
    // reads: logical chunk 'quad' -> physical chunk quad ^ ((row>>3)&1)<<1
    const int rq8   = ((quad ^ (((l16 >> 3) & 1) << 1)) << 3);
    const int a_off = ((wm*80 + l16) << 5) + rq8;
    const int b_off = ((wn*64 + l16) << 5) + rq8;

    // per-wave staging source pointers / LDS dest offsets (static-indexed)
    const unsigned short* asrc[5]; int adst[5];
    #pragma unroll
    for (int p = 0; p < 5; ++p){
        int j = 5*w + p, kh = j/20, g = j - kh*20;
        asrc[p] = Ag + (long)(m0 + g*16 + (l >> 2))*KP + (kh << 5) + (schunk << 3);
        adst[p] = kh*AH_STR + g*512;
    }
    const unsigned short* bsrc[2]; int bdst[2];
    #pragma unroll
    for (int q = 0; q < 2; ++q){
        int j = 2*w + q, kh = j >> 3, g = j & 7;
        bsrc[q] = Bg + (long)(n0 + g*16 + (l >> 2))*KP + (kh << 5) + (schunk << 3);
        bdst[q] = kh*BH_STR + g*512;
    }

    f32x4 acc[5][4];
    #pragma unroll
    for (int i = 0; i < 5; ++i)
        #pragma unroll
        for (int j = 0; j < 4; ++j)
            #pragma unroll
            for (int r = 0; r < 4; ++r) acc[i][j][r] = 0.f;

    // prologue: A(0),B(0)->buf0 [7], A(1),B(1)->buf1 [7]; drain tile-0's 7 only.
    #pragma unroll
    for (int p = 0; p < 5; ++p) STG_A(0, 0, p);
    #pragma unroll
    for (int q = 0; q < 2; ++q) STG_B(0, 0, q);
    #pragma unroll
    for (int p = 0; p < 5; ++p) STG_A(1, AB_STR, p);
    #pragma unroll
    for (int q = 0; q < 2; ++q) STG_B(1, BB_STR, q);
    GATE7;
    BARR;

    int ab = 0, bb = 0;   // buf of tile t: ab = t%3, bb = t&1
    #pragma unroll 1
    for (int t = 0; t < KTILES-2; ++t){
        const int pA  = ab*AB_STR;
        const int pB  = bb*BB_STR;                   // B(t) buf == B(t+2) dest buf
        const int ab2 = (ab == 0) ? 2 : ab - 1;      // (t+2)%3
        const int pA2 = ab2*AB_STR;
        TILE_BODY({ STG_A(t+2,pA2,0); STG_A(t+2,pA2,1); STG_A(t+2,pA2,2); STG_A(t+2,pA2,3); },
                  { STG_A(t+2,pA2,4); STG_B(t+2,pB,0); STG_B(t+2,pB,1); },
                  GATE7)
        ab = (ab == 2) ? 0 : ab + 1;
        bb ^= 1;
    }
    // peeled tile KTILES-2: no staging; full drain (tile-45's loads -> tile-47 data)
    {
        const int pA = ab*AB_STR, pB = bb*BB_STR;
        TILE_BODY(NOOPS, NOOPS, GATE0)
        ab = (ab == 2) ? 0 : ab + 1;
        bb ^= 1;
    }
    // peeled tile KTILES-1: no staging, no gate
    {
        const int pA = ab*AB_STR, pB = bb*BB_STR;
        TILE_BODY(NOOPS, NOOPS, NOOPS)
    }

    // epilogue: C/D layout col=lane&15, row=quad*4+reg
    #pragma unroll
    for (int mt = 0; mt < 5; ++mt){
        const int rowb = m0 + wm*80 + mt*16 + quad*4;
        #pragma unroll
        for (int nt = 0; nt < 4; ++nt){
            const int col = n0 + wn*64 + nt*16 + l16;
            #pragma unroll
            for (int r = 0; r < 4; ++r){
                const int row = rowb + r;
                if (row < M) C[(long)row*Cstride + col] = f2b(acc[mt][nt][r]);
            }
        }
    }
}

// ---------------- 64x64 MFMA GEMM: C = A[ridx?] @ BT^T (+epi) ----------------
// A: MxK bf16, BT: NnxK bf16, K % 64 == 0. epi: 0 none, 1 +bias, 2 +bias+prelu.
// obf: output bf16 (else f32). ridx: optional A row gather.
// K-unrolled x2: 64 k-cols staged per barrier round (halves barrier count).
// colsum != nullptr: additionally atomicAdd per-column sums of acc (NO bias) --
// used to fuse the DGI mean reduction into the posZ GEMM (bias folded in ws_k).
__device__ __forceinline__ void gemm_bt_body(
    const unsigned short* __restrict__ A,
    const unsigned short* __restrict__ BT,
    void* __restrict__ Cv,
    int M, int Nn, int K, int Cstride,
    const float* __restrict__ bias,
    const float* __restrict__ alpha,
    int epi, const int* __restrict__ ridx, int obf,
    float* __restrict__ colsum)
{
    __shared__ __align__(16) unsigned short As[2][64*40];
    __shared__ __align__(16) unsigned short Bs[2][64*40];
    const int m0 = blockIdx.y*64, n0 = blockIdx.x*64;
    const int t = threadIdx.x;
    const int lrow = t >> 2, lk = (t & 3) * 8;
    const int wave = t >> 6, lane = t & 63;
    const int quad = lane >> 4, l16 = lane & 15;
    f32x4 acc[4];
    #pragma unroll
    for (int i = 0; i < 4; i++)
        for (int j = 0; j < 4; j++) acc[i][j] = 0.f;

    const bool arv = (m0 + lrow) < M;
    const bool brv = (n0 + lrow) < Nn;
    long arow = 0;
    if (arv) arow = ridx ? (long)ridx[m0 + lrow] : (long)(m0 + lrow);
    const long arowbase = arow * K;
    const long browbase = (long)(n0 + lrow) * K;

    for (int k0 = 0; k0 < K; k0 += 64){
        uint4 av0 = {0u,0u,0u,0u}, av1 = {0u,0u,0u,0u};
        uint4 bv0 = {0u,0u,0u,0u}, bv1 = {0u,0u,0u,0u};
        if (arv){
            av0 = *(const uint4*)(A + arowbase + k0 + lk);
            av1 = *(const uint4*)(A + arowbase + k0 + 32 + lk);
        }
        if (brv){
            bv0 = *(const uint4*)(BT + browbase + k0 + lk);
            bv1 = *(const uint4*)(BT + browbase + k0 + 32 + lk);
        }
        *(uint4*)(&As[0][lrow*40 + lk]) = av0;
        *(uint4*)(&As[1][lrow*40 + lk]) = av1;
        *(uint4*)(&Bs[0][lrow*40 + lk]) = bv0;
        *(uint4*)(&Bs[1][lrow*40 + lk]) = bv1;
        __syncthreads();
        #pragma unroll
        for (int ks = 0; ks < 2; ++ks){
            bf16x8 af = *(const bf16x8*)(&As[ks][(wave*16 + l16)*40 + quad*8]);
            #pragma unroll
            for (int nt = 0; nt < 4; nt++){
                bf16x8 bfr = *(const bf16x8*)(&Bs[ks][(nt*16 + l16)*40 + quad*8]);
                acc[nt] = __builtin_amdgcn_mfma_f32_16x16x32_bf16(af, bfr, acc[nt], 0, 0, 0);
            }
        }
        __syncthreads();
    }

    const int rowb = m0 + wave*16 + quad*4;
    float aval = (epi == 2) ? alpha[0] : 0.f;
    #pragma unroll
    for (int nt = 0; nt < 4; nt++){
        int col = n0 + nt*16 + l16;
        if (col >= Nn) continue;
        float bvv = epi ? bias[col] : 0.f;
        #pragma unroll
        for (int r = 0; r < 4; r++){
            int row = rowb + r;
            if (row < M){
                float v = acc[nt][r] + bvv;
                if (epi == 2 && v < 0.f) v *= aval;
                if (obf) ((unsigned short*)Cv)[(long)row*Cstride + col] = f2b(v);
                else     ((float*)Cv)[(long)row*Cstride + col] = v;
            }
        }
    }

    if (colsum){
        // per-block column reduction of raw acc (invalid rows contribute 0).
        __syncthreads();
        float* cs = (float*)As;   // reuse LDS: 64 cols x 16 contributors
        #pragma unroll
        for (int nt = 0; nt < 4; nt++){
            float s = acc[nt][0] + acc[nt][1] + acc[nt][2] + acc[nt][3];
            cs[(nt*16 + l16)*16 + (wave*4 + quad)] = s;
        }
        __syncthreads();
        if (t < 64){
            float s = 0.f;
            #pragma unroll
            for (int j = 0; j < 16; ++j) s += cs[t*16 + j];
            atomicAdd(&colsum[n0 + t], s);
        }
    }
}

__global__ __launch_bounds__(256) void gemm_bt_ex(
    const unsigned short* __restrict__ A,
    const unsigned short* __restrict__ BT,
    void* __restrict__ Cv,
    int M, int Nn, int K, int Cstride,
    const float* __restrict__ bias,
    const float* __restrict__ alpha,
    int epi, const int* __restrict__ ridx, int obf)
{
    gemm_bt_body(A, BT, Cv, M, Nn, K, Cstride, bias, alpha, epi, ridx, obf, nullptr);
}

// z-batched pair variant: blockIdx.z selects the (A,B,C,bias,alpha) set.
// cs0: optional column-sum target for set 0 (posZ DGI mean fusion).
__global__ __launch_bounds__(256) void gemm_bt2(
    const unsigned short* __restrict__ A0, const unsigned short* __restrict__ A1,
    const unsigned short* __restrict__ B0, const unsigned short* __restrict__ B1,
    void* __restrict__ C0, void* __restrict__ C1,
    int M, int Nn, int K, int Cstride,
    const float* __restrict__ bias0, const float* __restrict__ bias1,
    const float* __restrict__ al0, const float* __restrict__ al1,
    int epi, const int* __restrict__ ridx, int obf,
    float* __restrict__ cs0)
{
    if (blockIdx.z == 0)
        gemm_bt_body(A0, B0, C0, M, Nn, K, Cstride, bias0, al0, epi, ridx, obf, cs0);
    else
        gemm_bt_body(A1, B1, C1, M, Nn, K, Cstride, bias1, al1, epi, ridx, obf, nullptr);
}

// 3-way fused launch: z=0/1 = projection-H (pos/neg, gathered rows, prelu),
// z=2 = decoder pre-matmul recPre (independent of both). Ragged grid with
// early-exit guards; launch (4, 157, 3).
__global__ __launch_bounds__(256) void gemm_bt3(
    const unsigned short* __restrict__ repP, const unsigned short* __restrict__ repN,
    const unsigned short* __restrict__ pW1T, const unsigned short* __restrict__ tpW1T,
    const unsigned short* __restrict__ e2dWT,
    unsigned short* __restrict__ posH, unsigned short* __restrict__ negH,
    unsigned short* __restrict__ recPre,
    const float* __restrict__ pb1, const float* __restrict__ tpb1,
    const float* __restrict__ pa, const float* __restrict__ tpa,
    const int* __restrict__ perm)
{
    int z = blockIdx.z;
    if (z == 0){
        if (blockIdx.y < 47)
            gemm_bt_body(repP, pW1T, posH, NM, PP, LL, PP, pb1, pa, 2, perm, 1, nullptr);
    } else if (z == 1){
        if (blockIdx.y < 47)
            gemm_bt_body(repN, tpW1T, negH, NM, PP, LL, PP, tpb1, tpa, 2, perm, 1, nullptr);
    } else {
        if (blockIdx.x < 2)
            gemm_bt_body(repP, e2dWT, recPre, NND, LL, LL, LL, nullptr, nullptr, 0, nullptr, 1, nullptr);
    }
}

// ---------------- fused GCN layer-1 aggregation (pos + neg), bf16 I/O ----------------
// warps 0-1: pos half (XW cols [0,512)); warps 2-3: neg half (cols [512,1024) of
// gathered negsrc rows). uint2 loads (4 cols/thread). flag branches are
// block-uniform -> masked neg gathers are SKIPPED entirely (~30% of edges).

__global__ __launch_bounds__(256) void agg1_k(const unsigned short* __restrict__ XW,
    const float* __restrict__ ptW, const float* __restrict__ ntW,
    const int* __restrict__ flag, const int* __restrict__ negsrc,
    const float* __restrict__ dinv, const int* __restrict__ rowptr,
    const int* __restrict__ degi, const int* __restrict__ adj,
    const float* __restrict__ sb1, const float* __restrict__ sav,
    const float* __restrict__ tb1, const float* __restrict__ tav,
    unsigned short* __restrict__ H1p, unsigned short* __restrict__ H1n)
{
    int i = blockIdx.x; int t = threadIdx.x;
    int half = t >> 7;          // 0 = pos, 1 = neg
    int c = (t & 127) * 4;      // cols c..c+3 in [0,512)
    float di = dinv[i];
    int rs = rowptr[i], re = rs + degi[i];
    int fi = flag[i];
    float a0, a1, a2, a3;

    if (half == 0){
        float p0 = ptW[c], p1 = ptW[c+1], p2 = ptW[c+2], p3 = ptW[c+3];
        uint2 v = *(const uint2*)(XW + (long)i*1024 + c);
        float2 va = bpair(v.x), vb = bpair(v.y);
        float ffi = fi ? 1.f : 0.f;
        a0 = (va.x + ffi*p0)*di; a1 = (va.y + ffi*p1)*di;
        a2 = (vb.x + ffi*p2)*di; a3 = (vb.y + ffi*p3)*di;
        for (int e = rs; e < re; ++e){
            int s = adj[e]; float ds = dinv[s];
            float ffs = flag[s] ? 1.f : 0.f;
            uint2 w = *(const uint2*)(XW + (long)s*1024 + c);
            float2 wa = bpair(w.x), wb = bpair(w.y);
            a0 += (wa.x + ffs*p0)*ds; a1 += (wa.y + ffs*p1)*ds;
            a2 += (wb.x + ffs*p2)*ds; a3 += (wb.y + ffs*p3)*ds;
        }
        float sa_ = sav[0];
        float v0 = di*a0 + sb1[c];   if (v0 < 0.f) v0 *= sa_;
        float v1 = di*a1 + sb1[c+1]; if (v1 < 0.f) v1 *= sa_;
        float v2 = di*a2 + sb1[c+2]; if (v2 < 0.f) v2 *= sa_;
        float v3 = di*a3 + sb1[c+3]; if (v3 < 0.f) v3 *= sa_;
        uint2 o; o.x = packb(v0, v1); o.y = packb(v2, v3);
        *(uint2*)(H1p + (long)i*512 + c) = o;
    } else {
        float n0 = ntW[c], n1 = ntW[c+1], n2 = ntW[c+2], n3 = ntW[c+3];
        if (fi){ a0 = n0*di; a1 = n1*di; a2 = n2*di; a3 = n3*di; }
        else {
            int nsi = negsrc[i];
            uint2 v = *(const uint2*)(XW + (long)nsi*1024 + 512 + c);
            float2 va = bpair(v.x), vb = bpair(v.y);
            a0 = va.x*di; a1 = va.y*di; a2 = vb.x*di; a3 = vb.y*di;
        }
        for (int e = rs; e < re; ++e){
            int s = adj[e]; float ds = dinv[s];
            if (flag[s]){ a0 += n0*ds; a1 += n1*ds; a2 += n2*ds; a3 += n3*ds; }
            else {
                int ns = negsrc[s];
                uint2 w = *(const uint2*)(XW + (long)ns*1024 + 512 + c);
                float2 wa = bpair(w.x), wb = bpair(w.y);
                a0 += wa.x*ds; a1 += wa.y*ds; a2 += wb.x*ds; a3 += wb.y*ds;
            }
        }
        float ta_ = tav[0];
        float v0 = di*a0 + tb1[c];   if (v0 < 0.f) v0 *= ta_;
        float v1 = di*a1 + tb1[c+1]; if (v1 < 0.f) v1 *= ta_;
        float v2 = di*a2 + tb1[c+2]; if (v2 < 0.f) v2 *= ta_;
        float v3 = di*a3 + tb1[c+3]; if (v3 < 0.f) v3 *= ta_;
        uint2 o; o.x = packb(v0, v1); o.y = packb(v2, v3);
        *(uint2*)(H1n + (long)i*512 + c) = o;
    }
}

// fused pos/neg second-layer aggregation: wave 0 = pos, wave 1 = neg (one block
// per node -> adj/dinv scalar loads shared via L1); uint loads (2 cols/thread).
__global__ __launch_bounds__(128) void agg128_k(
    const unsigned short* __restrict__ In0, const unsigned short* __restrict__ In1,
    const float* __restrict__ dinv, const int* __restrict__ rowptr,
    const int* __restrict__ degi, const int* __restrict__ adj,
    const float* __restrict__ b20, const float* __restrict__ b21,
    const float* __restrict__ a20, const float* __restrict__ a21,
    unsigned short* __restrict__ Out0, unsigned short* __restrict__ Out1)
{
    int i = blockIdx.x, t = threadIdx.x;
    int h = t >> 6;
    int c = (t & 63) * 2;
    const unsigned short* In = h ? In1 : In0;
    const float* b2 = h ? b21 : b20;
    const float* a2 = h ? a21 : a20;
    unsigned short* Out = h ? Out1 : Out0;
    float di = dinv[i];
    int rs = rowptr[i], re = rs + degi[i];
    float2 sv = bpair(*(const unsigned int*)(In + (long)i*128 + c));
    float acc0 = sv.x * di, acc1 = sv.y * di;
    for (int e = rs; e < re; ++e){
        int s = adj[e]; float ds = dinv[s];
        float2 w = bpair(*(const unsigned int*)(In + (long)s*128 + c));
        acc0 += w.x * ds; acc1 += w.y * ds;
    }
    float a = a2[0];
    float v0 = di*acc0 + b2[c];   if (v0 < 0.f) v0 *= a;
    float v1 = di*acc1 + b2[c+1]; if (v1 < 0.f) v1 *= a;
    *(unsigned int*)(Out + (long)i*128 + c) = packb(v0, v1);
}

// decoder aggregation over unmasked neighbors; uint loads, masked gathers skipped.
__global__ __launch_bounds__(64) void aggrec_k(const unsigned short* __restrict__ recPre,
    const float* __restrict__ dinv, const int* __restrict__ rowptr,
    const int* __restrict__ degi, const int* __restrict__ adj,
    const int* __restrict__ flag, const int* __restrict__ perm,
    unsigned short* __restrict__ recAgg)
{
    int b = blockIdx.x, t = threadIdx.x;
    int c = t * 2;
    int i = perm[b];
    float di = dinv[i];
    int rs = rowptr[i], re = rs + degi[i];
    float acc0 = 0.f, acc1 = 0.f; // self loop: i is a mask node -> rec row zeroed
    for (int e = rs; e < re; ++e){
        int s = adj[e];
        if (!flag[s]){
            float ds = dinv[s];
            float2 w = bpair(*(const unsigned int*)(recPre + (long)s*128 + c));
            acc0 += w.x * ds; acc1 += w.y * ds;
        }
    }
    *(unsigned int*)(recAgg + (long)b*128 + c) = packb(di*acc0, di*acc1);
}

// ---------------- DGI head ----------------
// (meanp fused into the posZ GEMM colsum epilogue; svecraw = colsum of raw acc,
//  bias folded analytically here: mean = svecraw/NM + pb2.)

__global__ void ws_k(const float* __restrict__ dgiW, const float* __restrict__ svecraw,
                     const float* __restrict__ pb2, float* wsv){
    __shared__ float s[128];
    int i = threadIdx.x; // 128
    s[i] = 1.f/(1.f + expf(-(svecraw[i]/(float)NM + pb2[i])));
    __syncthreads();
    float a = 0.f;
    for (int j = 0; j < 128; ++j) a += dgiW[i*128 + j] * s[j];
    wsv[i] = a;
}

// grid-stride rows; per-wave accumulate; 2 atomics per block.
__global__ __launch_bounds__(256) void dgi_k(const float* __restrict__ posZ,
    const float* __restrict__ negZ, const float* __restrict__ wsv, float* scal){
    __shared__ float sp[4], sn[4];
    int wid = threadIdx.x >> 6, lane = threadIdx.x & 63;
    float w0 = wsv[lane], w1 = wsv[64 + lane];
    float accp = 0.f, accn = 0.f;
    for (int row = blockIdx.x*4 + wid; row < 2*NM; row += gridDim.x*4){
        const float* Z = (row < NM) ? posZ : negZ;
        int r = (row < NM) ? row : row - NM;
        float v = Z[(long)r*128 + lane] * w0 + Z[(long)r*128 + 64 + lane] * w1;
        for (int off = 32; off; off >>= 1) v += __shfl_down(v, off, 64);
        if (lane == 0){
            float d = 1.f/(1.f + expf(-v));
            if (row < NM) accp += logf(d + 1e-15f);
            else          accn += logf(1.f - d + 1e-15f);
        }
    }
    if (lane == 0){ sp[wid] = accp; sn[wid] = accn; }
    __syncthreads();
    if (threadIdx.x == 0){
        atomicAdd(&scal[0], sp[0]+sp[1]+sp[2]+sp[3]);
        atomicAdd(&scal[1], sn[0]+sn[1]+sn[2]+sn[3]);
    }
}

// ---------------- cosine feature loss ----------------
// 8 cols/thread: float4 x reads, uint4 recMask reads.

__global__ __launch_bounds__(256) void cos_k(const float* __restrict__ x,
    const unsigned short* __restrict__ recMask, const int* __restrict__ perm,
    float* scal){
    int b = blockIdx.x, t = threadIdx.x;
    long xi = (long)perm[b]*DD;
    long ri = (long)b*DD;
    float dot = 0.f, nx = 0.f, nr = 0.f;
    for (int d0 = t*8; d0 < DD; d0 += 2048){
        float4 xa = *(const float4*)(x + xi + d0);
        float4 xb2 = *(const float4*)(x + xi + d0 + 4);
        uint4 rv = *(const uint4*)(recMask + ri + d0);
        float2 r0 = bpair(rv.x), r1 = bpair(rv.y), r2 = bpair(rv.z), r3 = bpair(rv.w);
        dot += xa.x*r0.x + xa.y*r0.y + xa.z*r1.x + xa.w*r1.y
             + xb2.x*r2.x + xb2.y*r2.y + xb2.z*r3.x + xb2.w*r3.y;
        nx  += xa.x*xa.x + xa.y*xa.y + xa.z*xa.z + xa.w*xa.w
             + xb2.x*xb2.x + xb2.y*xb2.y + xb2.z*xb2.z + xb2.w*xb2.w;
        nr  += r0.x*r0.x + r0.y*r0.y + r1.x*r1.x + r1.y*r1.y
             + r2.x*r2.x + r2.y*r2.y + r3.x*r3.x + r3.y*r3.y;
    }
    for (int off = 32; off; off >>= 1){
        dot += __shfl_down(dot, off, 64);
        nx  += __shfl_down(nx,  off, 64);
        nr  += __shfl_down(nr,  off, 64);
    }
    __shared__ float sd[4], sx[4], sr[4];
    int w = t >> 6, lane = t & 63;
    if (lane == 0){ sd[w] = dot; sx[w] = nx; sr[w] = nr; }
    __syncthreads();
    if (t == 0){
        float Dv = sd[0]+sd[1]+sd[2]+sd[3];
        float Xv = sx[0]+sx[1]+sx[2]+sx[3];
        float Rv = sr[0]+sr[1]+sr[2]+sr[3];
        float c = Dv/(fmaxf(sqrtf(Xv),1e-12f)*fmaxf(sqrtf(Rv),1e-12f));
        float e = 1.f - c;
        atomicAdd(&scal[16 + (b & 63)], e*e);   // 64-way spread -> ~47 per slot
    }
}

__global__ void fin_k(const float* __restrict__ scal, float* out){
    float fs = 0.f;
    for (int i = 0; i < 64; ++i) fs += scal[16 + i];
    float feat = fs/(float)NM;
    float dgi  = -(scal[0]/(float)NM) - (scal[1]/(float)NM);
    out[0] = feat;
    out[1] = dgi;
}

// ---------------- launch ----------------

extern "C" void kernel_launch(void* const* d_in, const int* in_sizes, int n_in,
                              void* d_out, int out_size, void* d_ws, size_t ws_size,
                              hipStream_t stream) {
    (void)in_sizes; (void)n_in; (void)out_size; (void)d_ws; (void)ws_size;
    const float* x  = (const float*)d_in[0];
    const int* ei   = (const int*)d_in[1];
    const int* perm = (const int*)d_in[2];
    const int* shuf = (const int*)d_in[3];
    const float* sW1 = (const float*)d_in[4];
    const float* sb1 = (const float*)d_in[5];
    const float* sa  = (const float*)d_in[6];
    const float* sW2 = (const float*)d_in[7];
    const float* sb2 = (const float*)d_in[8];
    const float* tW1 = (const float*)d_in[9];
    const float* tb1 = (const float*)d_in[10];
    const float* ta  = (const float*)d_in[11];
    const float* tW2 = (const float*)d_in[12];
    const float* tb2 = (const float*)d_in[13];
    const float* pW1 = (const float*)d_in[14];
    const float* pb1 = (const float*)d_in[15];
    const float* pa  = (const float*)d_in[16];
    const float* pW2 = (const float*)d_in[17];
    const float* pb2 = (const float*)d_in[18];
    const float* tpW1 = (const float*)d_in[19];
    const float* tpb1 = (const float*)d_in[20];
    const float* tpa  = (const float*)d_in[21];
    const float* tpW2 = (const float*)d_in[22];
    const float* tpb2 = (const float*)d_in[23];
    const float* dgiW = (const float*)d_in[24];
    const float* posT = (const float*)d_in[25];
    const float* negT = (const float*)d_in[26];
    const float* e2dW = (const float*)d_in[27];
    const float* dW   = (const float*)d_in[28];
    const float* db   = (const float*)d_in[29];
    float* out = (float*)d_out;

    void* wsp = nullptr;
    hipGetSymbolAddress(&wsp, HIP_SYMBOL(g_ws));
    char* base = (char*)wsp;
    size_t off = 0;
    auto alloc = [&](size_t b){ size_t o = off; off = (off + b + 255) & ~(size_t)255; return o; };

    float* dinv    = (float*)(base + alloc(NND*4));
    int* degi      = (int*)  (base + alloc(NND*4));
    int* rowptr    = (int*)  (base + alloc(NND*4));
    int* cursor    = (int*)  (base + alloc(NND*4));
    int* adj       = (int*)  (base + alloc(EE*4));
    int* flag      = (int*)  (base + alloc(NND*4));
    int* negsrc    = (int*)  (base + alloc(NND*4));
    int* ecnt      = (int*)  (base + alloc(16*4));
    float* ptW     = (float*)(base + alloc(HH*4));
    float* ntW     = (float*)(base + alloc(HH*4));
    float* svecraw = (float*)(base + alloc(128*4));
    float* wsv     = (float*)(base + alloc(128*4));
    float* scal    = (float*)(base + alloc(80*4));

    unsigned short* xb    = (unsigned short*)(base + alloc((size_t)MP*KP*2));
    unsigned short* W1T   = (unsigned short*)(base + alloc((size_t)NW*KP*2));
    unsigned short* sW2T  = (unsigned short*)(base + alloc((size_t)LL*HH*2));
    unsigned short* tW2T  = (unsigned short*)(base + alloc((size_t)LL*HH*2));
    unsigned short* pW1T  = (unsigned short*)(base + alloc((size_t)PP*LL*2));
    unsigned short* pW2T  = (unsigned short*)(base + alloc((size_t)LL*PP*2));
    unsigned short* tpW1T = (unsigned short*)(base + alloc((size_t)PP*LL*2));
    unsigned short* tpW2T = (unsigned short*)(base + alloc((size_t)LL*PP*2));
    unsigned short* e2dWT = (unsigned short*)(base + alloc((size_t)LL*LL*2));
    unsigned short* dWT   = (unsigned short*)(base + alloc((size_t)DD*LL*2));

    unsigned short* XW      = (unsigned short*)(base + alloc((size_t)NND*1024*2));
    unsigned short* H1p     = (unsigned short*)(base + alloc((size_t)NND*512*2));
    unsigned short* H1n     = (unsigned short*)(base + alloc((size_t)NND*512*2));
    unsigned short* M2p     = (unsigned short*)(base + alloc((size_t)NND*128*2));
    unsigned short* M2n     = (unsigned short*)(base + alloc((size_t)NND*128*2));
    unsigned short* repP    = (unsigned short*)(base + alloc((size_t)NND*128*2));
    unsigned short* repN    = (unsigned short*)(base + alloc((size_t)NND*128*2));
    unsigned short* posH    = (unsigned short*)(base + alloc((size_t)NM*256*2));
    unsigned short* negH    = (unsigned short*)(base + alloc((size_t)NM*256*2));
    float* posZ             = (float*)(base + alloc((size_t)NM*128*4));
    float* negZ             = (float*)(base + alloc((size_t)NM*128*4));
    unsigned short* recPre  = (unsigned short*)(base + alloc((size_t)NND*128*2));
    unsigned short* recAgg  = (unsigned short*)(base + alloc((size_t)NM*128*2));
    unsigned short* recMask = (unsigned short*)(base + alloc((size_t)NM*DD*2));

    // ---- graph build (scan-free) ----
    init_k<<<(NND+255)/256, 256, 0, stream>>>(degi, cursor, scal, ptW, ntW, svecraw, ecnt);
    build_k<<<(EE+255)/256, 256, 0, stream>>>(ei, perm, shuf, degi, flag, negsrc);
    alloc_k<<<(NND+255)/256, 256, 0, stream>>>(degi, dinv, rowptr, ecnt);
    fill_k<<<(EE+255)/256, 256, 0, stream>>>(ei, rowptr, cursor, adj);

    // ---- bf16 staging + token sums (single mega dispatch, grid-strided cast) ----
    {
        TBatch tb;
        const float* ins[10] = {sW1, tW1, sW2, tW2, pW1, pW2, tpW1, tpW2, e2dW, dW};
        unsigned short* outs[10] = {W1T, W1T + (size_t)HH*KP, sW2T, tW2T, pW1T, pW2T,
                                    tpW1T, tpW2T, e2dWT, dWT};
        int Rs[10]  = {DD, DD, HH, HH, LL, PP, LL, PP, LL, LL};
        int Cs[10]  = {HH, HH, LL, LL, PP, LL, PP, LL, LL, DD};
        int OSs[10] = {KP, KP, HH, HH, LL, PP, LL, PP, LL, LL};
        int cum = 0;
        for (int d = 0; d < 10; d++){
            tb.in[d] = ins[d]; tb.out[d] = outs[d];
            tb.R[d] = Rs[d]; tb.C[d] = Cs[d]; tb.OS[d] = OSs[d];
            tb.t0[d] = cum;
            cum += (OSs[d]/32) * ((Cs[d] + 31)/32);
        }
        tb.t0[10] = cum;
        stage_k<<<CAST_BLOCKS + cum + 256, 256, 0, stream>>>(tb, x, xb, posT, negT,
                                                             sW1, tW1, ptW, ntW);
    }

    // ---- encoder layer 1 (MFMA 320x128, 256 blocks) + fused aggregation ----
    gemm320<<<256, 512, 0, stream>>>(xb, W1T, XW, NND, 1024);
    agg1_k<<<NND, 256, 0, stream>>>(XW, ptW, ntW, flag, negsrc, dinv, rowptr, degi, adj,
                                    sb1, sa, tb1, ta, H1p, H1n);

    // ---- encoder layer 2 (MFMA, z-batched pair) + fused aggregation ----
    gemm_bt2<<<dim3(2,157,2), 256, 0, stream>>>(H1p, H1n, sW2T, tW2T, M2p, M2n,
                                                NND, LL, HH, LL,
                                                nullptr, nullptr, nullptr, nullptr,
                                                0, nullptr, 1, nullptr);
    agg128_k<<<NND, 128, 0, stream>>>(M2p, M2n, dinv, rowptr, degi, adj,
                                      sb2, tb2, sa, ta, repP, repN);

    // ---- projections-H (pos+neg) + decoder recPre, one ragged z=3 launch ----
    gemm_bt3<<<dim3(4,157,3), 256, 0, stream>>>(repP, repN, pW1T, tpW1T, e2dWT,
                                                posH, negH, recPre,
                                                pb1, tpb1, pa, tpa, perm);
    // posZ/negZ; posZ side also accumulates DGI column sums (meanp fused).
    gemm_bt2<<<dim3(2,47,2), 256, 0, stream>>>(posH, negH, pW2T, tpW2T, posZ, negZ,
                                               NM, LL, PP, LL,
                                               pb2, tpb2, nullptr, nullptr, 1, nullptr, 0,
                                               svecraw);

    // ---- decoder aggregation + reconstruction ----
    aggrec_k<<<NM, 64, 0, stream>>>(recPre, dinv, rowptr, degi, adj, flag, perm, recAgg);
    gemm_bt_ex<<<dim3(47,47), 256, 0, stream>>>(recAgg, dWT, recMask, NM, DD, LL, DD,
                                                db, nullptr, 1, nullptr, 1);

    // ---- DGI loss ----
    ws_k<<<1, 128, 0, stream>>>(dgiW, svecraw, pb2, wsv);
    dgi_k<<<128, 256, 0, stream>>>(posZ, negZ, wsv, scal);

    // ---- feature loss ----
    cos_k<<<NM, 256, 0, stream>>>(x, recMask, perm, scal);

    fin_k<<<1, 1, 0, stream>>>(scal, out);
}